// Round 16
// baseline (303.710 us; speedup 1.0000x reference)
//
#include <hip/hip_runtime.h>

// Problem constants
#define BB 16
#define TT 32
#define NN 1024
#define DD 64
#define HH 64
#define BN 16384          // B*N
#define GH 128
#define RR 128
#define OO 32

#define LOG2E 1.44269504088896f

typedef __attribute__((ext_vector_type(8))) short short8;
typedef __attribute__((ext_vector_type(4))) float f32x4;
typedef __attribute__((ext_vector_type(8))) _Float16 half8;
typedef __attribute__((ext_vector_type(2))) __fp16 fp16x2;

#define MF16(A, B, C) __builtin_amdgcn_mfma_f32_16x16x32_f16((A), (B), (C), 0, 0, 0)

// v_rcp_f32 (~1 ULP): plain 1/x without fast-math is ~10 VALU + ~40cy chain.
__device__ __forceinline__ float rcp_fast(float x) {
  return __builtin_amdgcn_rcpf(x);
}
__device__ __forceinline__ float exp2_fast(float x) {
  return __builtin_amdgcn_exp2f(x);
}
// Gate funcs taking PRE-SCALED (by log2e) pre-activations.
__device__ __forceinline__ float sigmoid2(float a) {   // a = x*log2e
  return rcp_fast(1.0f + exp2_fast(-a));
}
__device__ __forceinline__ float tanh2(float a) {      // a = x*log2e
  return fmaf(-2.0f, rcp_fast(exp2_fast(2.0f * a) + 1.0f), 1.0f);
}
// tanh of an UNSCALED argument via exp2 (libm tanhf without fast-math is a
// long branchy expansion -- same miss class as the fdiv in R12).
__device__ __forceinline__ float tanh_e(float x) {
  return tanh2(x * LOG2E);
}
__device__ __forceinline__ float leaky02(float x) {
  return fmaxf(x, 0.2f * x);
}

// ---------------------------------------------------------------------------
// Fused 2-layer GRU, v7 (unchanged from R15).
// ---------------------------------------------------------------------------
__global__ __launch_bounds__(512, 4) void gru_fused_kernel(
    const float* __restrict__ x,
    const float* __restrict__ Wih0, const float* __restrict__ Whh0,
    const float* __restrict__ bih0, const float* __restrict__ bhh0,
    const float* __restrict__ Wih1, const float* __restrict__ Whh1,
    const float* __restrict__ bih1, const float* __restrict__ bhh1,
    float* __restrict__ feat)
{
  __shared__ _Float16 sX[2][1024];     // [buf][seq*64 + swz(k)] : 4 KB
  __shared__ _Float16 sH0[2][1024];    // [buf][...] : 4 KB
  __shared__ _Float16 sH1[2][1024];    // [buf][...] : 4 KB

  const int tid = threadIdx.x;
  const int gbase = blockIdx.x * 16;

  const int w = tid >> 6, l = tid & 63;
  const int layer = w >> 2;            // 0 or 1
  const int jt = w & 3;                // 16-col j-group
  const int c = l & 15;                // A row (seq) / D col (j)
  const int rq = l >> 4;               // A k-chunk / D row-group

  const float* Wih = layer ? Wih1 : Wih0;
  const float* Whh = layer ? Whh1 : Whh0;
  const float* bihp = layer ? bih1 : bih0;
  const float* bhhp = layer ? bhh1 : bhh0;

  // ---- weight fragments: global -> reg, fp16 single-plane, x log2e ----
  half8 wf[3][2][2];
#pragma unroll
  for (int g = 0; g < 3; ++g) {
    const int row = g * 64 + jt * 16 + c;
#pragma unroll
    for (int ks = 0; ks < 2; ++ks) {
      const int col = ks * 32 + (rq << 3);
      float4 i0 = *reinterpret_cast<const float4*>(Wih + row * 64 + col);
      float4 i1 = *reinterpret_cast<const float4*>(Wih + row * 64 + col + 4);
      float4 h0 = *reinterpret_cast<const float4*>(Whh + row * 64 + col);
      float4 h1 = *reinterpret_cast<const float4*>(Whh + row * 64 + col + 4);
      float wi[8] = {i0.x, i0.y, i0.z, i0.w, i1.x, i1.y, i1.z, i1.w};
      float wh[8] = {h0.x, h0.y, h0.z, h0.w, h1.x, h1.y, h1.z, h1.w};
      half8 vih, vhh;
#pragma unroll
      for (int e = 0; e < 8; ++e) {
        vih[e] = (_Float16)(wi[e] * LOG2E);
        vhh[e] = (_Float16)(wh[e] * LOG2E);
      }
      wf[g][0][ks] = vih;
      wf[g][1][ks] = vhh;
    }
  }

  // ---- X staging role ----
  const int sseq = tid >> 5;           // 0..15
  const int kp = (tid & 31) << 1;      // even k
  const float* xrow = x + (size_t)(gbase + sseq) * (TT * 64) + kp;
  const int sxoff = sseq * 64 + (kp ^ ((sseq & 7) << 3));

  for (int i = tid; i < 1024; i += 512) {
    sH0[0][i] = (_Float16)0.0f;
    sH1[0][i] = (_Float16)0.0f;
  }

  float2 p = *reinterpret_cast<const float2*>(xrow);
  *reinterpret_cast<fp16x2*>(&sX[0][sxoff]) = __builtin_amdgcn_cvt_pkrtz(p.x, p.y);
  p = *reinterpret_cast<const float2*>(xrow + 64);

  // biases for this thread's j column (x log2e)
  const int jj = jt * 16 + c;
  const float br  = (bihp[jj]       + bhhp[jj])      * LOG2E;
  const float bz  = (bihp[64 + jj]  + bhhp[64 + jj]) * LOG2E;
  const float bni = bihp[128 + jj] * LOG2E;
  const float bnh = bhhp[128 + jj] * LOG2E;

  int ao[2];
#pragma unroll
  for (int ks = 0; ks < 2; ++ks)
    ao[ks] = c * 64 + (((ks << 5) + (rq << 3)) ^ ((c & 7) << 3));
  int hoff[4];
#pragma unroll
  for (int q = 0; q < 4; ++q) {
    const int seq = (rq << 2) + q;
    hoff[q] = seq * 64 + (jj ^ ((seq & 7) << 3));
  }

  float h[4] = {0.0f, 0.0f, 0.0f, 0.0f};

  for (int t = 0; t <= TT; ++t) {
    __syncthreads();
    const int cb = t & 1, nb = cb ^ 1;
    if (t + 1 < TT)
      *reinterpret_cast<fp16x2*>(&sX[nb][sxoff]) = __builtin_amdgcn_cvt_pkrtz(p.x, p.y);
    if (t + 2 < TT)
      p = *reinterpret_cast<const float2*>(xrow + (t + 2) * 64);

    const bool active = layer ? (t >= 1) : (t < TT);
    if (active) {
      const _Float16* xsrc = layer ? &sH0[cb][0] : &sX[cb][0];
      const _Float16* hsrc = layer ? &sH1[nb][0] : &sH0[cb][0];
      _Float16* hdst       = layer ? &sH1[cb][0] : &sH0[nb][0];

      f32x4 accr  = (f32x4){br, br, br, br};
      f32x4 accz  = (f32x4){bz, bz, bz, bz};
      f32x4 accni = (f32x4){bni, bni, bni, bni};
      f32x4 accnh = (f32x4){bnh, bnh, bnh, bnh};

#pragma unroll
      for (int ks = 0; ks < 2; ++ks) {
        const half8 xa = *reinterpret_cast<const half8*>(xsrc + ao[ks]);
        const half8 ha = *reinterpret_cast<const half8*>(hsrc + ao[ks]);
        accr  = MF16(xa, wf[0][0][ks], accr);
        accr  = MF16(ha, wf[0][1][ks], accr);
        accz  = MF16(xa, wf[1][0][ks], accz);
        accz  = MF16(ha, wf[1][1][ks], accz);
        accni = MF16(xa, wf[2][0][ks], accni);
        accnh = MF16(ha, wf[2][1][ks], accnh);
      }

#pragma unroll
      for (int q = 0; q < 4; ++q) {
        float rg = sigmoid2(accr[q]);
        float zg = sigmoid2(accz[q]);
        float ng = tanh2(fmaf(rg, accnh[q], accni[q]));
        float hv = fmaf(zg, h[q] - ng, ng);   // n + z*(h-n)
        h[q] = hv;
        hdst[hoff[q]] = (_Float16)hv;
      }
    }
  }

  if (layer == 1) {
#pragma unroll
    for (int q = 0; q < 4; ++q) {
      const int seq = (rq << 2) + q;
      feat[(size_t)(gbase + seq) * 64 + jj] = h[q];
    }
  }
}

// ---------------------------------------------------------------------------
// GAT projection, v2: 64 rows/block (256 blocks) -- the 8-row version
// re-staged the 32KB gatW per 8 rows = 8x redundant L2 traffic. Inner loop
// reads sFeat via float4 broadcast (quarter the LDS issue count).
// LDS 49 KB -> 3 blocks/CU.
// ---------------------------------------------------------------------------
__global__ __launch_bounds__(256) void gat_feat_kernel(
    const float* __restrict__ feat, const float* __restrict__ gatW,
    const float* __restrict__ a_src, const float* __restrict__ a_dst,
    float* __restrict__ Wh, float* __restrict__ srcv, float* __restrict__ dstv)
{
  __shared__ float sGatW[64 * 128];        // 32 KB
  __shared__ __align__(16) float sFeat[64][64];  // 16 KB
  __shared__ float sAs[128], sAd[128];
  const int tid = threadIdx.x;
  const int rowbase = blockIdx.x * 64;
  for (int idx = tid; idx < 8192; idx += 256) sGatW[idx] = gatW[idx];
  if (tid < 128) { sAs[tid] = a_src[tid]; sAd[tid] = a_dst[tid]; }
  for (int idx = tid; idx < 4096; idx += 256)
    sFeat[idx >> 6][idx & 63] = feat[(size_t)rowbase * 64 + idx];
  __syncthreads();

  const int hf = tid & 127, half = tid >> 7;
  const int h = hf >> 5;
  const float as = sAs[hf], ad = sAd[hf];
  for (int rr = half; rr < 64; rr += 2) {
    float acc = 0.0f;
#pragma unroll 4
    for (int k4 = 0; k4 < 16; ++k4) {
      const float4 fv = *reinterpret_cast<const float4*>(&sFeat[rr][k4 << 2]);
      acc = fmaf(fv.x, sGatW[((k4 << 2) + 0) * 128 + hf], acc);
      acc = fmaf(fv.y, sGatW[((k4 << 2) + 1) * 128 + hf], acc);
      acc = fmaf(fv.z, sGatW[((k4 << 2) + 2) * 128 + hf], acc);
      acc = fmaf(fv.w, sGatW[((k4 << 2) + 3) * 128 + hf], acc);
    }
    const size_t grow = rowbase + rr;
    Wh[grow * 128 + hf] = acc;
    float ps = acc * as, pd = acc * ad;
#pragma unroll
    for (int m = 16; m >= 1; m >>= 1) {
      ps += __shfl_xor(ps, m, 32);
      pd += __shfl_xor(pd, m, 32);
    }
    if ((hf & 31) == 0) {
      srcv[grow * 4 + h] = ps;
      dstv[grow * 4 + h] = pd;
    }
  }
}

// ---------------------------------------------------------------------------
// Attention + gat aggregation, v5 (unchanged from R15).
// ---------------------------------------------------------------------------
__global__ __launch_bounds__(256) void attn_kernel(
    const float* __restrict__ Wh, const float* __restrict__ srcp,
    const float* __restrict__ dstp, const int* __restrict__ adj,
    float* __restrict__ attn_out, float* __restrict__ gat_out)
{
  __shared__ __align__(16) float sDst[4096];          // 16 KB (x log2e)
  __shared__ __align__(16) float sSrc[128];           // (x log2e)
  __shared__ __align__(16) float sIS[128];            // 1/sum (or -1 sentinel)
  __shared__ unsigned int sAdjW[32][32];              // 4 KB bitmask
  __shared__ __align__(16) _Float16 sP[2][4][32][40]; // [buf][h][i][j] 20 KB
  __shared__ __align__(16) _Float16 sB[2][4][32][40]; // [buf][h][f][j] 20 KB

  const int tid = threadIdx.x;
  const int bid = blockIdx.x;
  const int swzb = ((bid & 7) << 6) | (bid >> 3);     // XCD-cluster swizzle
  const int b = swzb >> 5;
  const int itile = (swzb & 31) << 5;

  // ---- stage dst, src (pre-scaled by log2e so exp(x) -> exp2(x')) ----
  for (int idx = tid; idx < 4096; idx += 256)
    sDst[idx] = dstp[(size_t)b * 4096 + idx] * LOG2E;
  if (tid < 128)
    sSrc[tid] = srcp[((size_t)b * 1024 + itile) * 4 + tid] * LOG2E;

  // ---- build adj bitmask ----
  {
    const int row = tid >> 3;
    const int w0 = (tid & 7) << 2;
    const int* arow_g = adj + (size_t)(itile + row) * 1024 + (w0 << 5);
#pragma unroll
    for (int wq = 0; wq < 4; ++wq) {
      unsigned int word = 0;
#pragma unroll
      for (int c4 = 0; c4 < 8; ++c4) {
        int4 v = *reinterpret_cast<const int4*>(arow_g + (wq << 5) + (c4 << 2));
        word |= (unsigned)((v.x != 0) ? 1 : 0) << (c4 * 4 + 0);
        word |= (unsigned)((v.y != 0) ? 1 : 0) << (c4 * 4 + 1);
        word |= (unsigned)((v.z != 0) ? 1 : 0) << (c4 * 4 + 2);
        word |= (unsigned)((v.w != 0) ? 1 : 0) << (c4 * 4 + 3);
      }
      sAdjW[row][w0 + wq] = word;
    }
  }
  __syncthreads();

  // ---- pass 1: row sums (m=0 softmax; logits bounded) ----
  {
    const int i = tid >> 3;
    const int par = tid & 7;
    const float4 sv = *reinterpret_cast<const float4*>(&sSrc[i * 4]);
    f32x4 acc = (f32x4){0.f, 0.f, 0.f, 0.f};
    const unsigned int bit0 = 1u << par;
    for (int kw = 0; kw < 32; ++kw) {
      const unsigned int word = sAdjW[i][kw];
#pragma unroll
      for (int e = 0; e < 4; ++e) {
        const int gj = (kw << 5) + (e << 3) + par;
        const float4 dv = *reinterpret_cast<const float4*>(&sDst[gj * 4]);
        const float mf = (word & (bit0 << (e << 3))) ? 1.0f : 0.0f;
        acc[0] = fmaf(mf, exp2_fast(leaky02(sv.x + dv.x)), acc[0]);
        acc[1] = fmaf(mf, exp2_fast(leaky02(sv.y + dv.y)), acc[1]);
        acc[2] = fmaf(mf, exp2_fast(leaky02(sv.z + dv.z)), acc[2]);
        acc[3] = fmaf(mf, exp2_fast(leaky02(sv.w + dv.w)), acc[3]);
      }
    }
#pragma unroll
    for (int m = 1; m < 8; m <<= 1) {
#pragma unroll
      for (int q = 0; q < 4; ++q) acc[q] += __shfl_xor(acc[q], m, 64);
    }
    if (par == 0) {
      float4 isv;
      isv.x = acc[0] > 0.f ? rcp_fast(acc[0]) : -1.0f;
      isv.y = acc[1] > 0.f ? rcp_fast(acc[1]) : -1.0f;
      isv.z = acc[2] > 0.f ? rcp_fast(acc[2]) : -1.0f;
      isv.w = acc[3] > 0.f ? rcp_fast(acc[3]) : -1.0f;
      *reinterpret_cast<float4*>(&sIS[i * 4]) = isv;
    }
  }
  __syncthreads();

  // ---- pass 2: 32 j-tiles of 32, single barrier per tile (dbuf) ----
  const int il = tid >> 3;          // 0..31 (i row)
  const int jsub = tid & 7;         // stride-8 j within tile (coalesced)
  const int wv = tid >> 6;          // wave id = head for MFMA phase
  const int l = tid & 63;
  const int jjB = tid & 31;         // B-staging: Wh row within tile
  const int fcB = tid >> 5;         // B-staging: 16-hf chunk

  const float4 sv4 = *reinterpret_cast<const float4*>(&sSrc[il * 4]);
  const float4 is4 = *reinterpret_cast<const float4*>(&sIS[il * 4]);
  f32x4* arow_out = reinterpret_cast<f32x4*>(
      attn_out + ((size_t)(b * 1024 + itile + il)) * 4096);

  f32x4 accg[2][2];
#pragma unroll
  for (int m = 0; m < 2; ++m)
#pragma unroll
    for (int n = 0; n < 2; ++n) accg[m][n] = (f32x4){0.f, 0.f, 0.f, 0.f};

  const int frow = l & 15, fchunk = l >> 4;

  for (int jt = 0; jt < 32; ++jt) {
    const int j0 = jt << 5;
    const int cur = jt & 1;
    // -- stage & write phase (overlaps other waves' MFMA of jt-1) --
    {
      const unsigned int word = sAdjW[il][jt];
#pragma unroll
      for (int q = 0; q < 4; ++q) {
        const int j = jsub + (q << 3);
        const int gj = j0 + j;
        const float4 dv = *reinterpret_cast<const float4*>(&sDst[gj * 4]);
        const float mf = (word & (1u << j)) ? 1.0f : 0.0f;
        f32x4 a4;
        float ex;
        ex = mf * exp2_fast(leaky02(sv4.x + dv.x)); a4[0] = ex * is4.x; if (is4.x < 0.f) a4[0] = 9.765625e-4f;
        ex = mf * exp2_fast(leaky02(sv4.y + dv.y)); a4[1] = ex * is4.y; if (is4.y < 0.f) a4[1] = 9.765625e-4f;
        ex = mf * exp2_fast(leaky02(sv4.z + dv.z)); a4[2] = ex * is4.z; if (is4.z < 0.f) a4[2] = 9.765625e-4f;
        ex = mf * exp2_fast(leaky02(sv4.w + dv.w)); a4[3] = ex * is4.w; if (is4.w < 0.f) a4[3] = 9.765625e-4f;
        __builtin_nontemporal_store(a4, &arow_out[gj]);
        sP[cur][0][il][j] = (_Float16)a4[0];
        sP[cur][1][il][j] = (_Float16)a4[1];
        sP[cur][2][il][j] = (_Float16)a4[2];
        sP[cur][3][il][j] = (_Float16)a4[3];
      }
      // B staging: Wh[j0+jjB][fcB*16..+16] -> sB[cur][h][f][jjB]
      const float* wrow = Wh + ((size_t)(b * 1024 + j0 + jjB)) * 128 + (fcB << 4);
#pragma unroll
      for (int c4 = 0; c4 < 4; ++c4) {
        float4 v = *reinterpret_cast<const float4*>(wrow + (c4 << 2));
        float vv[4] = {v.x, v.y, v.z, v.w};
#pragma unroll
        for (int e = 0; e < 4; ++e) {
          const int hf = (fcB << 4) + (c4 << 2) + e;
          sB[cur][hf >> 5][hf & 31][jjB] = (_Float16)vv[e];
        }
      }
    }
    __syncthreads();
    // -- MFMA phase: wave wv handles head wv (4 MF16) --
    {
      half8 pa[2], wb[2];
#pragma unroll
      for (int m = 0; m < 2; ++m)
        pa[m] = *reinterpret_cast<const half8*>(&sP[cur][wv][m * 16 + frow][fchunk << 3]);
#pragma unroll
      for (int n = 0; n < 2; ++n)
        wb[n] = *reinterpret_cast<const half8*>(&sB[cur][wv][n * 16 + frow][fchunk << 3]);
#pragma unroll
      for (int m = 0; m < 2; ++m)
#pragma unroll
        for (int n = 0; n < 2; ++n)
          accg[m][n] = MF16(pa[m], wb[n], accg[m][n]);
    }
  }

  // ---- epilogue: elu + store gat ----
#pragma unroll
  for (int m = 0; m < 2; ++m)
#pragma unroll
    for (int n = 0; n < 2; ++n)
#pragma unroll
      for (int q = 0; q < 4; ++q) {
        const int i = m * 16 + (l >> 4) * 4 + q;
        const int f = n * 16 + (l & 15);
        float v = accg[m][n][q];
        v = v > 0.0f ? v : (exp2_fast(v * LOG2E) - 1.0f);
        gat_out[((size_t)(b * 1024 + itile + i)) * 128 + wv * 32 + f] = v;
      }
}

// ---------------------------------------------------------------------------
// MLP chain (tanh via exp2/rcp instead of libm tanhf).
// ---------------------------------------------------------------------------
__global__ __launch_bounds__(256) void mlp_kernel(
    const float* __restrict__ gat,
    const float* __restrict__ rW1, const float* __restrict__ rb1,
    const float* __restrict__ rW2, const float* __restrict__ rb2,
    const float* __restrict__ fW,  const float* __restrict__ fb,
    const float* __restrict__ ln_g, const float* __restrict__ ln_b,
    const float* __restrict__ nW1, const float* __restrict__ nb1,
    const float* __restrict__ nW2, const float* __restrict__ nb2,
    float* __restrict__ out)
{
  __shared__ float sW[128 * 128];
  __shared__ float sZ[16][128];
  __shared__ float sT[16][128];
  __shared__ float sY[16][32];
  __shared__ float sT2[16][32];
  __shared__ float sB1[128], sB2[128];

  const int tid = threadIdx.x;
  const int rowbase = blockIdx.x * 16;

  for (int idx = tid; idx < 16384; idx += 256) sW[idx] = rW1[idx];
  if (tid < 128) { sB1[tid] = rb1[tid]; sB2[tid] = rb2[tid]; }
  for (int idx = tid; idx < 2048; idx += 256)
    sZ[idx >> 7][idx & 127] = gat[(size_t)rowbase * 128 + idx];
  __syncthreads();

  const int c = tid & 127, rblk = tid >> 7;
  for (int q = 0; q < 8; ++q) {
    const int r = rblk + (q << 1);
    float a = sB1[c];
#pragma unroll 8
    for (int k = 0; k < 128; ++k) a = fmaf(sZ[r][k], sW[k * 128 + c], a);
    sT[r][c] = a > 0.0f ? a : 0.0f;
  }
  __syncthreads();
  for (int idx = tid; idx < 16384; idx += 256) sW[idx] = rW2[idx];
  __syncthreads();
  for (int q = 0; q < 8; ++q) {
    const int r = rblk + (q << 1);
    float a = sB2[c];
#pragma unroll 8
    for (int k = 0; k < 128; ++k) a = fmaf(sT[r][k], sW[k * 128 + c], a);
    a += sZ[r][c];
    sZ[r][c] = a > 0.0f ? a : 0.0f;
  }
  __syncthreads();
  for (int idx = tid; idx < 4096; idx += 256) sW[idx] = fW[idx];
  for (int idx = tid; idx < 1024; idx += 256) {
    sW[4096 + idx] = nW1[idx];
    sW[5120 + idx] = nW2[idx];
  }
  if (tid < 32) {
    sW[6144 + tid] = fb[tid];
    sW[6176 + tid] = ln_g[tid];
    sW[6208 + tid] = ln_b[tid];
    sW[6240 + tid] = nb1[tid];
    sW[6272 + tid] = nb2[tid];
  }
  __syncthreads();

  const int o = tid & 31, rr2 = tid >> 5;
  for (int g = 0; g < 2; ++g) {
    const int r = rr2 + (g << 3);
    float y = sW[6144 + o];
#pragma unroll 8
    for (int k = 0; k < 128; ++k) y = fmaf(sZ[r][k], sW[k * 32 + o], y);
    float mu = y;
#pragma unroll
    for (int m = 16; m >= 1; m >>= 1) mu += __shfl_xor(mu, m, 32);
    mu *= (1.0f / 32.0f);
    const float d = y - mu;
    float var = d * d;
#pragma unroll
    for (int m = 16; m >= 1; m >>= 1) var += __shfl_xor(var, m, 32);
    var *= (1.0f / 32.0f);
    const float yn = d * rsqrtf(var + 1e-5f) * sW[6176 + o] + sW[6208 + o];
    sY[r][o] = tanh_e(yn);
  }
  __syncthreads();
  for (int g = 0; g < 2; ++g) {
    const int r = rr2 + (g << 3);
    float a = sW[6240 + o];
#pragma unroll
    for (int k = 0; k < 32; ++k) a = fmaf(sY[r][k], sW[4096 + k * 32 + o], a);
    sT2[r][o] = a > 0.0f ? a : 0.0f;
  }
  __syncthreads();
  for (int g = 0; g < 2; ++g) {
    const int r = rr2 + (g << 3);
    float a = sW[6272 + o];
#pragma unroll
    for (int k = 0; k < 32; ++k) a = fmaf(sT2[r][k], sW[5120 + k * 32 + o], a);
    out[(size_t)(rowbase + r) * 32 + o] = a;
  }
}

// ---------------------------------------------------------------------------
extern "C" void kernel_launch(void* const* d_in, const int* in_sizes, int n_in,
                              void* d_out, int out_size, void* d_ws, size_t ws_size,
                              hipStream_t stream) {
  const float* seq   = (const float*)d_in[0];
  const int*   adj   = (const int*)d_in[1];
  const float* Wih0  = (const float*)d_in[2];
  const float* Whh0  = (const float*)d_in[3];
  const float* bih0  = (const float*)d_in[4];
  const float* bhh0  = (const float*)d_in[5];
  const float* Wih1  = (const float*)d_in[6];
  const float* Whh1  = (const float*)d_in[7];
  const float* bih1  = (const float*)d_in[8];
  const float* bhh1  = (const float*)d_in[9];
  const float* gatW  = (const float*)d_in[10];
  const float* a_src = (const float*)d_in[11];
  const float* a_dst = (const float*)d_in[12];
  const float* rW1   = (const float*)d_in[13];
  const float* rb1   = (const float*)d_in[14];
  const float* rW2   = (const float*)d_in[15];
  const float* rb2   = (const float*)d_in[16];
  const float* fW    = (const float*)d_in[17];
  const float* fb    = (const float*)d_in[18];
  const float* ln_g  = (const float*)d_in[19];
  const float* ln_b  = (const float*)d_in[20];
  const float* nW1   = (const float*)d_in[21];
  const float* nb1   = (const float*)d_in[22];
  const float* nW2   = (const float*)d_in[23];
  const float* nb2   = (const float*)d_in[24];

  float* out  = (float*)d_out;                  // [BN][32] at offset 0
  float* attn = out + (size_t)BN * OO;          // [B,N,N,4] region (268MB)

  float* ws   = (float*)d_ws;
  float* feat = ws;                             // [BN][64]
  float* Wh   = feat + (size_t)BN * 64;         // [BN][128]
  float* srcv = Wh + (size_t)BN * 128;          // [BN][4]
  float* dstv = srcv + (size_t)BN * 4;          // [BN][4]
  float* gat  = dstv + (size_t)BN * 4;          // [BN][128]

  gru_fused_kernel<<<1024, 512, 0, stream>>>(seq, Wih0, Whh0, bih0, bhh0,
                                             Wih1, Whh1, bih1, bhh1, feat);
  gat_feat_kernel<<<256, 256, 0, stream>>>(feat, gatW, a_src, a_dst, Wh, srcv, dstv);
  attn_kernel<<<512, 256, 0, stream>>>(Wh, srcv, dstv, adj, attn, gat);
  mlp_kernel<<<1024, 256, 0, stream>>>(gat, rW1, rb1, rW2, rb2, fW, fb,
                                       ln_g, ln_b, nW1, nb1, nW2, nb2, out);
}

// Round 17
// 299.183 us; speedup vs baseline: 1.0151x; 1.0151x over previous
//
#include <hip/hip_runtime.h>

// Problem constants
#define BB 16
#define TT 32
#define NN 1024
#define DD 64
#define HH 64
#define BN 16384          // B*N
#define GH 128
#define RR 128
#define OO 32

#define LOG2E 1.44269504088896f

typedef __attribute__((ext_vector_type(8))) short short8;
typedef __attribute__((ext_vector_type(4))) float f32x4;
typedef __attribute__((ext_vector_type(8))) _Float16 half8;
typedef __attribute__((ext_vector_type(2))) __fp16 fp16x2;

#define MF16(A, B, C) __builtin_amdgcn_mfma_f32_16x16x32_f16((A), (B), (C), 0, 0, 0)

__device__ __forceinline__ float rcp_fast(float x) {
  return __builtin_amdgcn_rcpf(x);
}
__device__ __forceinline__ float exp2_fast(float x) {
  return __builtin_amdgcn_exp2f(x);
}
__device__ __forceinline__ float sigmoid2(float a) {   // a = x*log2e
  return rcp_fast(1.0f + exp2_fast(-a));
}
__device__ __forceinline__ float tanh2(float a) {      // a = x*log2e
  return fmaf(-2.0f, rcp_fast(exp2_fast(2.0f * a) + 1.0f), 1.0f);
}
__device__ __forceinline__ float tanh_e(float x) {
  return tanh2(x * LOG2E);
}
__device__ __forceinline__ float leaky02(float x) {
  return fmaxf(x, 0.2f * x);
}

// ---------------------------------------------------------------------------
// Fused 2-layer GRU, v8 = v7 with 32 seqs/block (512 blocks = EXACTLY one
// scheduling round at 2 blocks/CU). v7's 1024 blocks ran 2 serial rounds;
// per-step fixed cost (barrier drain + ds_read latency + gate chain,
// measured ~2300 cyc/step) was paid 66x instead of 33x. Per wave/step now:
// 8 ds_read_b128 + 24 MFMA + 8 gate sets (2 M-tiles of 16 seqs).
// VGPR ~110 < 128 cap (launch_bounds(512,4)); LDS 24 KB -> 2 blocks/CU.
// ---------------------------------------------------------------------------
__global__ __launch_bounds__(512, 4) void gru_fused_kernel(
    const float* __restrict__ x,
    const float* __restrict__ Wih0, const float* __restrict__ Whh0,
    const float* __restrict__ bih0, const float* __restrict__ bhh0,
    const float* __restrict__ Wih1, const float* __restrict__ Whh1,
    const float* __restrict__ bih1, const float* __restrict__ bhh1,
    float* __restrict__ feat)
{
  __shared__ _Float16 sX[2][2048];     // [buf][seq*64 + swz(k)] : 8 KB
  __shared__ _Float16 sH0[2][2048];    // 8 KB
  __shared__ _Float16 sH1[2][2048];    // 8 KB

  const int tid = threadIdx.x;
  const int gbase = blockIdx.x * 32;

  const int w = tid >> 6, l = tid & 63;
  const int layer = w >> 2;            // 0 or 1
  const int jt = w & 3;                // 16-col j-group
  const int c = l & 15;                // D col (j) / A row within M-tile
  const int rq = l >> 4;               // A k-chunk / D row-group

  const float* Wih = layer ? Wih1 : Wih0;
  const float* Whh = layer ? Whh1 : Whh0;
  const float* bihp = layer ? bih1 : bih0;
  const float* bhhp = layer ? bhh1 : bhh0;

  // ---- weight fragments: global -> reg, fp16 single-plane, x log2e ----
  half8 wf[3][2][2];
#pragma unroll
  for (int g = 0; g < 3; ++g) {
    const int row = g * 64 + jt * 16 + c;
#pragma unroll
    for (int ks = 0; ks < 2; ++ks) {
      const int col = ks * 32 + (rq << 3);
      float4 i0 = *reinterpret_cast<const float4*>(Wih + row * 64 + col);
      float4 i1 = *reinterpret_cast<const float4*>(Wih + row * 64 + col + 4);
      float4 h0 = *reinterpret_cast<const float4*>(Whh + row * 64 + col);
      float4 h1 = *reinterpret_cast<const float4*>(Whh + row * 64 + col + 4);
      float wi[8] = {i0.x, i0.y, i0.z, i0.w, i1.x, i1.y, i1.z, i1.w};
      float wh[8] = {h0.x, h0.y, h0.z, h0.w, h1.x, h1.y, h1.z, h1.w};
      half8 vih, vhh;
#pragma unroll
      for (int e = 0; e < 8; ++e) {
        vih[e] = (_Float16)(wi[e] * LOG2E);
        vhh[e] = (_Float16)(wh[e] * LOG2E);
      }
      wf[g][0][ks] = vih;
      wf[g][1][ks] = vhh;
    }
  }

  // ---- X staging role: thread -> (seq = tid>>4 (0..31), k4 = (tid&15)*4) ----
  const int sseq = tid >> 4;
  const int kq = (tid & 15) << 2;
  const float* xrow = x + (size_t)(gbase + sseq) * (TT * 64) + kq;
  const int sxoff = sseq * 64 + (kq ^ ((sseq & 7) << 3));  // 4-chunk stays contiguous

  // zero-init H buffers read at first active steps
  for (int i = tid; i < 2048; i += 512) {
    sH0[0][i] = (_Float16)0.0f;
    sH1[0][i] = (_Float16)0.0f;
  }

  // prologue: stage X(0); preload X(1)
  float4 p = *reinterpret_cast<const float4*>(xrow);
  *reinterpret_cast<fp16x2*>(&sX[0][sxoff])     = __builtin_amdgcn_cvt_pkrtz(p.x, p.y);
  *reinterpret_cast<fp16x2*>(&sX[0][sxoff + 2]) = __builtin_amdgcn_cvt_pkrtz(p.z, p.w);
  p = *reinterpret_cast<const float4*>(xrow + 64);

  // biases for this thread's j column (x log2e)
  const int jj = jt * 16 + c;
  const float br  = (bihp[jj]       + bhhp[jj])      * LOG2E;
  const float bz  = (bihp[64 + jj]  + bhhp[64 + jj]) * LOG2E;
  const float bni = bihp[128 + jj] * LOG2E;
  const float bnh = bhhp[128 + jj] * LOG2E;

  // A-frag offsets for 2 M-tiles; (mi*16+c)&7 == c&7, swizzle invariant
  int ao[2][2];
#pragma unroll
  for (int mi = 0; mi < 2; ++mi)
#pragma unroll
    for (int ks = 0; ks < 2; ++ks)
      ao[mi][ks] = (mi * 16 + c) * 64 + (((ks << 5) + (rq << 3)) ^ ((c & 7) << 3));
  int hoff[2][4];
#pragma unroll
  for (int mi = 0; mi < 2; ++mi)
#pragma unroll
    for (int q = 0; q < 4; ++q) {
      const int seq = mi * 16 + (rq << 2) + q;
      hoff[mi][q] = seq * 64 + (jj ^ ((seq & 7) << 3));
    }

  float h[2][4];
#pragma unroll
  for (int mi = 0; mi < 2; ++mi)
#pragma unroll
    for (int q = 0; q < 4; ++q) h[mi][q] = 0.0f;

  // Buffer-parity audit (single barrier per step), same as v7:
  //  iter t: cb=t&1, nb=cb^1.
  //  L0 reads sX[cb] + sH0[cb], writes sH0[nb].
  //  L1 reads sH0[cb] + sH1[nb], writes sH1[cb].
  //  Staging writes sX[nb] = X(t+1); last readers of sX[nb] ran at t-1.
  for (int t = 0; t <= TT; ++t) {
    __syncthreads();
    const int cb = t & 1, nb = cb ^ 1;
    if (t + 1 < TT) {
      *reinterpret_cast<fp16x2*>(&sX[nb][sxoff])     = __builtin_amdgcn_cvt_pkrtz(p.x, p.y);
      *reinterpret_cast<fp16x2*>(&sX[nb][sxoff + 2]) = __builtin_amdgcn_cvt_pkrtz(p.z, p.w);
    }
    if (t + 2 < TT)
      p = *reinterpret_cast<const float4*>(xrow + (t + 2) * 64);

    const bool active = layer ? (t >= 1) : (t < TT);
    if (active) {
      const _Float16* xsrc = layer ? &sH0[cb][0] : &sX[cb][0];
      const _Float16* hsrc = layer ? &sH1[nb][0] : &sH0[cb][0];
      _Float16* hdst       = layer ? &sH1[cb][0] : &sH0[nb][0];

      f32x4 accr[2], accz[2], accni[2], accnh[2];
#pragma unroll
      for (int mi = 0; mi < 2; ++mi) {
        accr[mi]  = (f32x4){br, br, br, br};
        accz[mi]  = (f32x4){bz, bz, bz, bz};
        accni[mi] = (f32x4){bni, bni, bni, bni};
        accnh[mi] = (f32x4){bnh, bnh, bnh, bnh};
      }

#pragma unroll
      for (int ks = 0; ks < 2; ++ks) {
#pragma unroll
        for (int mi = 0; mi < 2; ++mi) {
          const half8 xa = *reinterpret_cast<const half8*>(xsrc + ao[mi][ks]);
          const half8 ha = *reinterpret_cast<const half8*>(hsrc + ao[mi][ks]);
          accr[mi]  = MF16(xa, wf[0][0][ks], accr[mi]);
          accr[mi]  = MF16(ha, wf[0][1][ks], accr[mi]);
          accz[mi]  = MF16(xa, wf[1][0][ks], accz[mi]);
          accz[mi]  = MF16(ha, wf[1][1][ks], accz[mi]);
          accni[mi] = MF16(xa, wf[2][0][ks], accni[mi]);
          accnh[mi] = MF16(ha, wf[2][1][ks], accnh[mi]);
        }
      }

#pragma unroll
      for (int mi = 0; mi < 2; ++mi)
#pragma unroll
        for (int q = 0; q < 4; ++q) {
          float rg = sigmoid2(accr[mi][q]);
          float zg = sigmoid2(accz[mi][q]);
          float ng = tanh2(fmaf(rg, accnh[mi][q], accni[mi][q]));
          float hv = fmaf(zg, h[mi][q] - ng, ng);   // n + z*(h-n)
          h[mi][q] = hv;
          hdst[hoff[mi][q]] = (_Float16)hv;
        }
    }
  }

  if (layer == 1) {
#pragma unroll
    for (int mi = 0; mi < 2; ++mi)
#pragma unroll
      for (int q = 0; q < 4; ++q) {
        const int seq = mi * 16 + (rq << 2) + q;
        feat[(size_t)(gbase + seq) * 64 + jj] = h[mi][q];
      }
  }
}

// ---------------------------------------------------------------------------
// GAT projection (reverted to R15 8-row version: 2048 blocks = 8/CU; R16's
// 64-row variant dropped to 1 block/CU and regressed ~5us; gatW staging
// redundancy is L2-absorbed).
// ---------------------------------------------------------------------------
__global__ __launch_bounds__(256) void gat_feat_kernel(
    const float* __restrict__ feat, const float* __restrict__ gatW,
    const float* __restrict__ a_src, const float* __restrict__ a_dst,
    float* __restrict__ Wh, float* __restrict__ srcv, float* __restrict__ dstv)
{
  __shared__ float sGatW[64 * 128];
  __shared__ float sFeat[8][64];
  __shared__ float sAs[128], sAd[128];
  const int tid = threadIdx.x;
  const int rowbase = blockIdx.x * 8;
  for (int idx = tid; idx < 8192; idx += 256) sGatW[idx] = gatW[idx];
  if (tid < 128) { sAs[tid] = a_src[tid]; sAd[tid] = a_dst[tid]; }
  for (int idx = tid; idx < 512; idx += 256)
    sFeat[idx >> 6][idx & 63] = feat[(size_t)rowbase * 64 + idx];
  __syncthreads();

  const int hf = tid & 127, half = tid >> 7;
  const int h = hf >> 5;
  const float as = sAs[hf], ad = sAd[hf];
  for (int rr = half; rr < 8; rr += 2) {
    float acc = 0.0f;
#pragma unroll 8
    for (int k = 0; k < 64; ++k) acc = fmaf(sFeat[rr][k], sGatW[k * 128 + hf], acc);
    const size_t grow = rowbase + rr;
    Wh[grow * 128 + hf] = acc;
    float ps = acc * as, pd = acc * ad;
#pragma unroll
    for (int m = 16; m >= 1; m >>= 1) {
      ps += __shfl_xor(ps, m, 32);
      pd += __shfl_xor(pd, m, 32);
    }
    if ((hf & 31) == 0) {
      srcv[grow * 4 + h] = ps;
      dstv[grow * 4 + h] = pd;
    }
  }
}

// ---------------------------------------------------------------------------
// Attention + gat aggregation, v5 (unchanged from R15).
// ---------------------------------------------------------------------------
__global__ __launch_bounds__(256) void attn_kernel(
    const float* __restrict__ Wh, const float* __restrict__ srcp,
    const float* __restrict__ dstp, const int* __restrict__ adj,
    float* __restrict__ attn_out, float* __restrict__ gat_out)
{
  __shared__ __align__(16) float sDst[4096];          // 16 KB (x log2e)
  __shared__ __align__(16) float sSrc[128];           // (x log2e)
  __shared__ __align__(16) float sIS[128];            // 1/sum (or -1 sentinel)
  __shared__ unsigned int sAdjW[32][32];              // 4 KB bitmask
  __shared__ __align__(16) _Float16 sP[2][4][32][40]; // [buf][h][i][j] 20 KB
  __shared__ __align__(16) _Float16 sB[2][4][32][40]; // [buf][h][f][j] 20 KB

  const int tid = threadIdx.x;
  const int bid = blockIdx.x;
  const int swzb = ((bid & 7) << 6) | (bid >> 3);     // XCD-cluster swizzle
  const int b = swzb >> 5;
  const int itile = (swzb & 31) << 5;

  // ---- stage dst, src (pre-scaled by log2e so exp(x) -> exp2(x')) ----
  for (int idx = tid; idx < 4096; idx += 256)
    sDst[idx] = dstp[(size_t)b * 4096 + idx] * LOG2E;
  if (tid < 128)
    sSrc[tid] = srcp[((size_t)b * 1024 + itile) * 4 + tid] * LOG2E;

  // ---- build adj bitmask ----
  {
    const int row = tid >> 3;
    const int w0 = (tid & 7) << 2;
    const int* arow_g = adj + (size_t)(itile + row) * 1024 + (w0 << 5);
#pragma unroll
    for (int wq = 0; wq < 4; ++wq) {
      unsigned int word = 0;
#pragma unroll
      for (int c4 = 0; c4 < 8; ++c4) {
        int4 v = *reinterpret_cast<const int4*>(arow_g + (wq << 5) + (c4 << 2));
        word |= (unsigned)((v.x != 0) ? 1 : 0) << (c4 * 4 + 0);
        word |= (unsigned)((v.y != 0) ? 1 : 0) << (c4 * 4 + 1);
        word |= (unsigned)((v.z != 0) ? 1 : 0) << (c4 * 4 + 2);
        word |= (unsigned)((v.w != 0) ? 1 : 0) << (c4 * 4 + 3);
      }
      sAdjW[row][w0 + wq] = word;
    }
  }
  __syncthreads();

  // ---- pass 1: row sums (m=0 softmax; logits bounded) ----
  {
    const int i = tid >> 3;
    const int par = tid & 7;
    const float4 sv = *reinterpret_cast<const float4*>(&sSrc[i * 4]);
    f32x4 acc = (f32x4){0.f, 0.f, 0.f, 0.f};
    const unsigned int bit0 = 1u << par;
    for (int kw = 0; kw < 32; ++kw) {
      const unsigned int word = sAdjW[i][kw];
#pragma unroll
      for (int e = 0; e < 4; ++e) {
        const int gj = (kw << 5) + (e << 3) + par;
        const float4 dv = *reinterpret_cast<const float4*>(&sDst[gj * 4]);
        const float mf = (word & (bit0 << (e << 3))) ? 1.0f : 0.0f;
        acc[0] = fmaf(mf, exp2_fast(leaky02(sv.x + dv.x)), acc[0]);
        acc[1] = fmaf(mf, exp2_fast(leaky02(sv.y + dv.y)), acc[1]);
        acc[2] = fmaf(mf, exp2_fast(leaky02(sv.z + dv.z)), acc[2]);
        acc[3] = fmaf(mf, exp2_fast(leaky02(sv.w + dv.w)), acc[3]);
      }
    }
#pragma unroll
    for (int m = 1; m < 8; m <<= 1) {
#pragma unroll
      for (int q = 0; q < 4; ++q) acc[q] += __shfl_xor(acc[q], m, 64);
    }
    if (par == 0) {
      float4 isv;
      isv.x = acc[0] > 0.f ? rcp_fast(acc[0]) : -1.0f;
      isv.y = acc[1] > 0.f ? rcp_fast(acc[1]) : -1.0f;
      isv.z = acc[2] > 0.f ? rcp_fast(acc[2]) : -1.0f;
      isv.w = acc[3] > 0.f ? rcp_fast(acc[3]) : -1.0f;
      *reinterpret_cast<float4*>(&sIS[i * 4]) = isv;
    }
  }
  __syncthreads();

  // ---- pass 2: 32 j-tiles of 32, single barrier per tile (dbuf) ----
  const int il = tid >> 3;          // 0..31 (i row)
  const int jsub = tid & 7;         // stride-8 j within tile (coalesced)
  const int wv = tid >> 6;          // wave id = head for MFMA phase
  const int l = tid & 63;
  const int jjB = tid & 31;         // B-staging: Wh row within tile
  const int fcB = tid >> 5;         // B-staging: 16-hf chunk

  const float4 sv4 = *reinterpret_cast<const float4*>(&sSrc[il * 4]);
  const float4 is4 = *reinterpret_cast<const float4*>(&sIS[il * 4]);
  f32x4* arow_out = reinterpret_cast<f32x4*>(
      attn_out + ((size_t)(b * 1024 + itile + il)) * 4096);

  f32x4 accg[2][2];
#pragma unroll
  for (int m = 0; m < 2; ++m)
#pragma unroll
    for (int n = 0; n < 2; ++n) accg[m][n] = (f32x4){0.f, 0.f, 0.f, 0.f};

  const int frow = l & 15, fchunk = l >> 4;

  for (int jt = 0; jt < 32; ++jt) {
    const int j0 = jt << 5;
    const int cur = jt & 1;
    // -- stage & write phase (overlaps other waves' MFMA of jt-1) --
    {
      const unsigned int word = sAdjW[il][jt];
#pragma unroll
      for (int q = 0; q < 4; ++q) {
        const int j = jsub + (q << 3);
        const int gj = j0 + j;
        const float4 dv = *reinterpret_cast<const float4*>(&sDst[gj * 4]);
        const float mf = (word & (1u << j)) ? 1.0f : 0.0f;
        f32x4 a4;
        float ex;
        ex = mf * exp2_fast(leaky02(sv4.x + dv.x)); a4[0] = ex * is4.x; if (is4.x < 0.f) a4[0] = 9.765625e-4f;
        ex = mf * exp2_fast(leaky02(sv4.y + dv.y)); a4[1] = ex * is4.y; if (is4.y < 0.f) a4[1] = 9.765625e-4f;
        ex = mf * exp2_fast(leaky02(sv4.z + dv.z)); a4[2] = ex * is4.z; if (is4.z < 0.f) a4[2] = 9.765625e-4f;
        ex = mf * exp2_fast(leaky02(sv4.w + dv.w)); a4[3] = ex * is4.w; if (is4.w < 0.f) a4[3] = 9.765625e-4f;
        __builtin_nontemporal_store(a4, &arow_out[gj]);
        sP[cur][0][il][j] = (_Float16)a4[0];
        sP[cur][1][il][j] = (_Float16)a4[1];
        sP[cur][2][il][j] = (_Float16)a4[2];
        sP[cur][3][il][j] = (_Float16)a4[3];
      }
      // B staging: Wh[j0+jjB][fcB*16..+16] -> sB[cur][h][f][jjB]
      const float* wrow = Wh + ((size_t)(b * 1024 + j0 + jjB)) * 128 + (fcB << 4);
#pragma unroll
      for (int c4 = 0; c4 < 4; ++c4) {
        float4 v = *reinterpret_cast<const float4*>(wrow + (c4 << 2));
        float vv[4] = {v.x, v.y, v.z, v.w};
#pragma unroll
        for (int e = 0; e < 4; ++e) {
          const int hf = (fcB << 4) + (c4 << 2) + e;
          sB[cur][hf >> 5][hf & 31][jjB] = (_Float16)vv[e];
        }
      }
    }
    __syncthreads();
    // -- MFMA phase: wave wv handles head wv (4 MF16) --
    {
      half8 pa[2], wb[2];
#pragma unroll
      for (int m = 0; m < 2; ++m)
        pa[m] = *reinterpret_cast<const half8*>(&sP[cur][wv][m * 16 + frow][fchunk << 3]);
#pragma unroll
      for (int n = 0; n < 2; ++n)
        wb[n] = *reinterpret_cast<const half8*>(&sB[cur][wv][n * 16 + frow][fchunk << 3]);
#pragma unroll
      for (int m = 0; m < 2; ++m)
#pragma unroll
        for (int n = 0; n < 2; ++n)
          accg[m][n] = MF16(pa[m], wb[n], accg[m][n]);
    }
  }

  // ---- epilogue: elu + store gat ----
#pragma unroll
  for (int m = 0; m < 2; ++m)
#pragma unroll
    for (int n = 0; n < 2; ++n)
#pragma unroll
      for (int q = 0; q < 4; ++q) {
        const int i = m * 16 + (l >> 4) * 4 + q;
        const int f = n * 16 + (l & 15);
        float v = accg[m][n][q];
        v = v > 0.0f ? v : (exp2_fast(v * LOG2E) - 1.0f);
        gat_out[((size_t)(b * 1024 + itile + i)) * 128 + wv * 32 + f] = v;
      }
}

// ---------------------------------------------------------------------------
// MLP chain (tanh via exp2/rcp).
// ---------------------------------------------------------------------------
__global__ __launch_bounds__(256) void mlp_kernel(
    const float* __restrict__ gat,
    const float* __restrict__ rW1, const float* __restrict__ rb1,
    const float* __restrict__ rW2, const float* __restrict__ rb2,
    const float* __restrict__ fW,  const float* __restrict__ fb,
    const float* __restrict__ ln_g, const float* __restrict__ ln_b,
    const float* __restrict__ nW1, const float* __restrict__ nb1,
    const float* __restrict__ nW2, const float* __restrict__ nb2,
    float* __restrict__ out)
{
  __shared__ float sW[128 * 128];
  __shared__ float sZ[16][128];
  __shared__ float sT[16][128];
  __shared__ float sY[16][32];
  __shared__ float sT2[16][32];
  __shared__ float sB1[128], sB2[128];

  const int tid = threadIdx.x;
  const int rowbase = blockIdx.x * 16;

  for (int idx = tid; idx < 16384; idx += 256) sW[idx] = rW1[idx];
  if (tid < 128) { sB1[tid] = rb1[tid]; sB2[tid] = rb2[tid]; }
  for (int idx = tid; idx < 2048; idx += 256)
    sZ[idx >> 7][idx & 127] = gat[(size_t)rowbase * 128 + idx];
  __syncthreads();

  const int c = tid & 127, rblk = tid >> 7;
  for (int q = 0; q < 8; ++q) {
    const int r = rblk + (q << 1);
    float a = sB1[c];
#pragma unroll 8
    for (int k = 0; k < 128; ++k) a = fmaf(sZ[r][k], sW[k * 128 + c], a);
    sT[r][c] = a > 0.0f ? a : 0.0f;
  }
  __syncthreads();
  for (int idx = tid; idx < 16384; idx += 256) sW[idx] = rW2[idx];
  __syncthreads();
  for (int q = 0; q < 8; ++q) {
    const int r = rblk + (q << 1);
    float a = sB2[c];
#pragma unroll 8
    for (int k = 0; k < 128; ++k) a = fmaf(sT[r][k], sW[k * 128 + c], a);
    a += sZ[r][c];
    sZ[r][c] = a > 0.0f ? a : 0.0f;
  }
  __syncthreads();
  for (int idx = tid; idx < 4096; idx += 256) sW[idx] = fW[idx];
  for (int idx = tid; idx < 1024; idx += 256) {
    sW[4096 + idx] = nW1[idx];
    sW[5120 + idx] = nW2[idx];
  }
  if (tid < 32) {
    sW[6144 + tid] = fb[tid];
    sW[6176 + tid] = ln_g[tid];
    sW[6208 + tid] = ln_b[tid];
    sW[6240 + tid] = nb1[tid];
    sW[6272 + tid] = nb2[tid];
  }
  __syncthreads();

  const int o = tid & 31, rr2 = tid >> 5;
  for (int g = 0; g < 2; ++g) {
    const int r = rr2 + (g << 3);
    float y = sW[6144 + o];
#pragma unroll 8
    for (int k = 0; k < 128; ++k) y = fmaf(sZ[r][k], sW[k * 32 + o], y);
    float mu = y;
#pragma unroll
    for (int m = 16; m >= 1; m >>= 1) mu += __shfl_xor(mu, m, 32);
    mu *= (1.0f / 32.0f);
    const float d = y - mu;
    float var = d * d;
#pragma unroll
    for (int m = 16; m >= 1; m >>= 1) var += __shfl_xor(var, m, 32);
    var *= (1.0f / 32.0f);
    const float yn = d * rsqrtf(var + 1e-5f) * sW[6176 + o] + sW[6208 + o];
    sY[r][o] = tanh_e(yn);
  }
  __syncthreads();
  for (int g = 0; g < 2; ++g) {
    const int r = rr2 + (g << 3);
    float a = sW[6240 + o];
#pragma unroll
    for (int k = 0; k < 32; ++k) a = fmaf(sY[r][k], sW[4096 + k * 32 + o], a);
    sT2[r][o] = a > 0.0f ? a : 0.0f;
  }
  __syncthreads();
  for (int g = 0; g < 2; ++g) {
    const int r = rr2 + (g << 3);
    float a = sW[6272 + o];
#pragma unroll
    for (int k = 0; k < 32; ++k) a = fmaf(sT2[r][k], sW[5120 + k * 32 + o], a);
    out[(size_t)(rowbase + r) * 32 + o] = a;
  }
}

// ---------------------------------------------------------------------------
extern "C" void kernel_launch(void* const* d_in, const int* in_sizes, int n_in,
                              void* d_out, int out_size, void* d_ws, size_t ws_size,
                              hipStream_t stream) {
  const float* seq   = (const float*)d_in[0];
  const int*   adj   = (const int*)d_in[1];
  const float* Wih0  = (const float*)d_in[2];
  const float* Whh0  = (const float*)d_in[3];
  const float* bih0  = (const float*)d_in[4];
  const float* bhh0  = (const float*)d_in[5];
  const float* Wih1  = (const float*)d_in[6];
  const float* Whh1  = (const float*)d_in[7];
  const float* bih1  = (const float*)d_in[8];
  const float* bhh1  = (const float*)d_in[9];
  const float* gatW  = (const float*)d_in[10];
  const float* a_src = (const float*)d_in[11];
  const float* a_dst = (const float*)d_in[12];
  const float* rW1   = (const float*)d_in[13];
  const float* rb1   = (const float*)d_in[14];
  const float* rW2   = (const float*)d_in[15];
  const float* rb2   = (const float*)d_in[16];
  const float* fW    = (const float*)d_in[17];
  const float* fb    = (const float*)d_in[18];
  const float* ln_g  = (const float*)d_in[19];
  const float* ln_b  = (const float*)d_in[20];
  const float* nW1   = (const float*)d_in[21];
  const float* nb1   = (const float*)d_in[22];
  const float* nW2   = (const float*)d_in[23];
  const float* nb2   = (const float*)d_in[24];

  float* out  = (float*)d_out;                  // [BN][32] at offset 0
  float* attn = out + (size_t)BN * OO;          // [B,N,N,4] region (268MB)

  float* ws   = (float*)d_ws;
  float* feat = ws;                             // [BN][64]
  float* Wh   = feat + (size_t)BN * 64;         // [BN][128]
  float* srcv = Wh + (size_t)BN * 128;          // [BN][4]
  float* dstv = srcv + (size_t)BN * 4;          // [BN][4]
  float* gat  = dstv + (size_t)BN * 4;          // [BN][128]

  gru_fused_kernel<<<512, 512, 0, stream>>>(seq, Wih0, Whh0, bih0, bhh0,
                                            Wih1, Whh1, bih1, bhh1, feat);
  gat_feat_kernel<<<2048, 256, 0, stream>>>(feat, gatW, a_src, a_dst, Wh, srcv, dstv);
  attn_kernel<<<512, 256, 0, stream>>>(Wh, srcv, dstv, adj, attn, gat);
  mlp_kernel<<<1024, 256, 0, stream>>>(gat, rW1, rb1, rW2, rb2, fW, fb,
                                       ln_g, ln_b, nW1, nb1, nW2, nb2, out);
}

// Round 18
// 279.923 us; speedup vs baseline: 1.0850x; 1.0688x over previous
//
#include <hip/hip_runtime.h>

// Problem constants
#define BB 16
#define TT 32
#define NN 1024
#define DD 64
#define HH 64
#define BN 16384          // B*N
#define GH 128
#define RR 128
#define OO 32

#define LOG2E 1.44269504088896f

typedef __attribute__((ext_vector_type(8))) short short8;
typedef __attribute__((ext_vector_type(4))) float f32x4;
typedef __attribute__((ext_vector_type(8))) _Float16 half8;
typedef __attribute__((ext_vector_type(2))) __fp16 fp16x2;

#define MF16(A, B, C) __builtin_amdgcn_mfma_f32_16x16x32_f16((A), (B), (C), 0, 0, 0)

__device__ __forceinline__ float rcp_fast(float x) {
  return __builtin_amdgcn_rcpf(x);
}
__device__ __forceinline__ float exp2_fast(float x) {
  return __builtin_amdgcn_exp2f(x);
}
__device__ __forceinline__ float sigmoid2(float a) {   // a = x*log2e
  return rcp_fast(1.0f + exp2_fast(-a));
}
__device__ __forceinline__ float tanh2(float a) {      // a = x*log2e
  return fmaf(-2.0f, rcp_fast(exp2_fast(2.0f * a) + 1.0f), 1.0f);
}
__device__ __forceinline__ float tanh_e(float x) {
  return tanh2(x * LOG2E);
}
__device__ __forceinline__ float leaky02(float x) {
  return fmaxf(x, 0.2f * x);
}

// ---------------------------------------------------------------------------
// Fused 2-layer GRU + GAT projection, v9 = v8 + fused epilogue.
// Block = 512 thr = 8 waves, 32 seqs, 512 blocks (one round, 2 blocks/CU).
// After the recurrence, h1 sits in sH1[0] (fp16, A-frag layout) -- the GAT
// projection Wh = h1 @ gatW is 4 MFMAs/wave (wave w = 16-col hf group) plus
// a 16-lane shuffle reduce for src/dst. Deletes the gat_feat kernel and the
// 8.4 MB feat global round-trip.
// ---------------------------------------------------------------------------
__global__ __launch_bounds__(512, 4) void gru_fused_kernel(
    const float* __restrict__ x,
    const float* __restrict__ Wih0, const float* __restrict__ Whh0,
    const float* __restrict__ bih0, const float* __restrict__ bhh0,
    const float* __restrict__ Wih1, const float* __restrict__ Whh1,
    const float* __restrict__ bih1, const float* __restrict__ bhh1,
    const float* __restrict__ gatW, const float* __restrict__ a_src,
    const float* __restrict__ a_dst,
    float* __restrict__ Wh, float* __restrict__ srcv, float* __restrict__ dstv)
{
  __shared__ _Float16 sX[2][2048];     // [buf][seq*64 + swz(k)] : 8 KB
  __shared__ _Float16 sH0[2][2048];    // 8 KB
  __shared__ _Float16 sH1[2][2048];    // 8 KB

  const int tid = threadIdx.x;
  const int gbase = blockIdx.x * 32;

  const int w = tid >> 6, l = tid & 63;
  const int layer = w >> 2;            // 0 or 1
  const int jt = w & 3;                // 16-col j-group
  const int c = l & 15;                // D col (j) / A row within M-tile
  const int rq = l >> 4;               // A k-chunk / D row-group

  const float* Wih = layer ? Wih1 : Wih0;
  const float* Whh = layer ? Whh1 : Whh0;
  const float* bihp = layer ? bih1 : bih0;
  const float* bhhp = layer ? bhh1 : bhh0;

  // ---- weight fragments: global -> reg, fp16 single-plane, x log2e ----
  half8 wf[3][2][2];
#pragma unroll
  for (int g = 0; g < 3; ++g) {
    const int row = g * 64 + jt * 16 + c;
#pragma unroll
    for (int ks = 0; ks < 2; ++ks) {
      const int col = ks * 32 + (rq << 3);
      float4 i0 = *reinterpret_cast<const float4*>(Wih + row * 64 + col);
      float4 i1 = *reinterpret_cast<const float4*>(Wih + row * 64 + col + 4);
      float4 h0 = *reinterpret_cast<const float4*>(Whh + row * 64 + col);
      float4 h1 = *reinterpret_cast<const float4*>(Whh + row * 64 + col + 4);
      float wi[8] = {i0.x, i0.y, i0.z, i0.w, i1.x, i1.y, i1.z, i1.w};
      float wh[8] = {h0.x, h0.y, h0.z, h0.w, h1.x, h1.y, h1.z, h1.w};
      half8 vih, vhh;
#pragma unroll
      for (int e = 0; e < 8; ++e) {
        vih[e] = (_Float16)(wi[e] * LOG2E);
        vhh[e] = (_Float16)(wh[e] * LOG2E);
      }
      wf[g][0][ks] = vih;
      wf[g][1][ks] = vhh;
    }
  }

  // ---- X staging role: thread -> (seq = tid>>4 (0..31), k4 = (tid&15)*4) ----
  const int sseq = tid >> 4;
  const int kq = (tid & 15) << 2;
  const float* xrow = x + (size_t)(gbase + sseq) * (TT * 64) + kq;
  const int sxoff = sseq * 64 + (kq ^ ((sseq & 7) << 3));  // 4-chunk stays contiguous

  // zero-init H buffers read at first active steps
  for (int i = tid; i < 2048; i += 512) {
    sH0[0][i] = (_Float16)0.0f;
    sH1[0][i] = (_Float16)0.0f;
  }

  // prologue: stage X(0); preload X(1)
  float4 p = *reinterpret_cast<const float4*>(xrow);
  *reinterpret_cast<fp16x2*>(&sX[0][sxoff])     = __builtin_amdgcn_cvt_pkrtz(p.x, p.y);
  *reinterpret_cast<fp16x2*>(&sX[0][sxoff + 2]) = __builtin_amdgcn_cvt_pkrtz(p.z, p.w);
  p = *reinterpret_cast<const float4*>(xrow + 64);

  // biases for this thread's j column (x log2e)
  const int jj = jt * 16 + c;
  const float br  = (bihp[jj]       + bhhp[jj])      * LOG2E;
  const float bz  = (bihp[64 + jj]  + bhhp[64 + jj]) * LOG2E;
  const float bni = bihp[128 + jj] * LOG2E;
  const float bnh = bhhp[128 + jj] * LOG2E;

  // A-frag offsets for 2 M-tiles; (mi*16+c)&7 == c&7, swizzle invariant
  int ao[2][2];
#pragma unroll
  for (int mi = 0; mi < 2; ++mi)
#pragma unroll
    for (int ks = 0; ks < 2; ++ks)
      ao[mi][ks] = (mi * 16 + c) * 64 + (((ks << 5) + (rq << 3)) ^ ((c & 7) << 3));
  int hoff[2][4];
#pragma unroll
  for (int mi = 0; mi < 2; ++mi)
#pragma unroll
    for (int q = 0; q < 4; ++q) {
      const int seq = mi * 16 + (rq << 2) + q;
      hoff[mi][q] = seq * 64 + (jj ^ ((seq & 7) << 3));
    }

  float h[2][4];
#pragma unroll
  for (int mi = 0; mi < 2; ++mi)
#pragma unroll
    for (int q = 0; q < 4; ++q) h[mi][q] = 0.0f;

  // Buffer-parity audit (single barrier per step):
  //  iter t: cb=t&1, nb=cb^1.
  //  L0 reads sX[cb] + sH0[cb], writes sH0[nb].
  //  L1 reads sH0[cb] + sH1[nb], writes sH1[cb].
  //  Final h1(T-1) written at t=32 into sH1[0].
  for (int t = 0; t <= TT; ++t) {
    __syncthreads();
    const int cb = t & 1, nb = cb ^ 1;
    if (t + 1 < TT) {
      *reinterpret_cast<fp16x2*>(&sX[nb][sxoff])     = __builtin_amdgcn_cvt_pkrtz(p.x, p.y);
      *reinterpret_cast<fp16x2*>(&sX[nb][sxoff + 2]) = __builtin_amdgcn_cvt_pkrtz(p.z, p.w);
    }
    if (t + 2 < TT)
      p = *reinterpret_cast<const float4*>(xrow + (t + 2) * 64);

    const bool active = layer ? (t >= 1) : (t < TT);
    if (active) {
      const _Float16* xsrc = layer ? &sH0[cb][0] : &sX[cb][0];
      const _Float16* hsrc = layer ? &sH1[nb][0] : &sH0[cb][0];
      _Float16* hdst       = layer ? &sH1[cb][0] : &sH0[nb][0];

      f32x4 accr[2], accz[2], accni[2], accnh[2];
#pragma unroll
      for (int mi = 0; mi < 2; ++mi) {
        accr[mi]  = (f32x4){br, br, br, br};
        accz[mi]  = (f32x4){bz, bz, bz, bz};
        accni[mi] = (f32x4){bni, bni, bni, bni};
        accnh[mi] = (f32x4){bnh, bnh, bnh, bnh};
      }

#pragma unroll
      for (int ks = 0; ks < 2; ++ks) {
#pragma unroll
        for (int mi = 0; mi < 2; ++mi) {
          const half8 xa = *reinterpret_cast<const half8*>(xsrc + ao[mi][ks]);
          const half8 ha = *reinterpret_cast<const half8*>(hsrc + ao[mi][ks]);
          accr[mi]  = MF16(xa, wf[0][0][ks], accr[mi]);
          accr[mi]  = MF16(ha, wf[0][1][ks], accr[mi]);
          accz[mi]  = MF16(xa, wf[1][0][ks], accz[mi]);
          accz[mi]  = MF16(ha, wf[1][1][ks], accz[mi]);
          accni[mi] = MF16(xa, wf[2][0][ks], accni[mi]);
          accnh[mi] = MF16(ha, wf[2][1][ks], accnh[mi]);
        }
      }

#pragma unroll
      for (int mi = 0; mi < 2; ++mi)
#pragma unroll
        for (int q = 0; q < 4; ++q) {
          float rg = sigmoid2(accr[mi][q]);
          float zg = sigmoid2(accz[mi][q]);
          float ng = tanh2(fmaf(rg, accnh[mi][q], accni[mi][q]));
          float hv = fmaf(zg, h[mi][q] - ng, ng);   // n + z*(h-n)
          h[mi][q] = hv;
          hdst[hoff[mi][q]] = (_Float16)hv;
        }
    }
  }

  // ---- fused GAT projection epilogue: Wh = h1 @ gatW (+ src/dst) ----
  __syncthreads();   // all sH1[0] writes visible
  float* sRed = reinterpret_cast<float*>(&sX[0][0]);  // reuse: 512 floats used
  {
    const int col = (w << 4) + c;     // hf column 0..127 (wave w = 16-col group)
    half8 gb[2];
#pragma unroll
    for (int ks = 0; ks < 2; ++ks)
#pragma unroll
      for (int e = 0; e < 8; ++e) {
        const int k = ks * 32 + (rq << 3) + e;
        gb[ks][e] = (_Float16)gatW[k * 128 + col];
      }
    const float as = a_src[col], ad = a_dst[col];
    f32x4 accw[2];
#pragma unroll
    for (int mi = 0; mi < 2; ++mi) {
      accw[mi] = (f32x4){0.f, 0.f, 0.f, 0.f};
#pragma unroll
      for (int ks = 0; ks < 2; ++ks) {
        const half8 fa = *reinterpret_cast<const half8*>(&sH1[0][0] + ao[mi][ks]);
        accw[mi] = MF16(fa, gb[ks], accw[mi]);
      }
    }
    // write Wh (D layout: row = mi*16 + rq*4 + q, col) + column partials
#pragma unroll
    for (int mi = 0; mi < 2; ++mi)
#pragma unroll
      for (int q = 0; q < 4; ++q) {
        const int seq = mi * 16 + (rq << 2) + q;
        Wh[(size_t)(gbase + seq) * 128 + col] = accw[mi][q];
        float s = accw[mi][q] * as, d = accw[mi][q] * ad;
#pragma unroll
        for (int mm = 1; mm < 16; mm <<= 1) {
          s += __shfl_xor(s, mm, 64);
          d += __shfl_xor(d, mm, 64);
        }
        if (c == 0) {
          sRed[w * 32 + seq]       = s;
          sRed[256 + w * 32 + seq] = d;
        }
      }
  }
  __syncthreads();
  // combine wave-pairs per head: head h covers waves 2h, 2h+1
  if (tid < 256) {
    const int hh = tid >> 6;          // head 0..3
    const int rem = tid & 63;
    const int sd = rem >> 5;          // 0 = src, 1 = dst
    const int ii = rem & 31;
    const float v = sRed[sd * 256 + (hh * 2) * 32 + ii] +
                    sRed[sd * 256 + (hh * 2 + 1) * 32 + ii];
    float* outp = sd ? dstv : srcv;
    outp[(size_t)(gbase + ii) * 4 + hh] = v;
  }
}

// ---------------------------------------------------------------------------
// Attention + gat aggregation, v5 (unchanged from R15).
// ---------------------------------------------------------------------------
__global__ __launch_bounds__(256) void attn_kernel(
    const float* __restrict__ Wh, const float* __restrict__ srcp,
    const float* __restrict__ dstp, const int* __restrict__ adj,
    float* __restrict__ attn_out, float* __restrict__ gat_out)
{
  __shared__ __align__(16) float sDst[4096];          // 16 KB (x log2e)
  __shared__ __align__(16) float sSrc[128];           // (x log2e)
  __shared__ __align__(16) float sIS[128];            // 1/sum (or -1 sentinel)
  __shared__ unsigned int sAdjW[32][32];              // 4 KB bitmask
  __shared__ __align__(16) _Float16 sP[2][4][32][40]; // [buf][h][i][j] 20 KB
  __shared__ __align__(16) _Float16 sB[2][4][32][40]; // [buf][h][f][j] 20 KB

  const int tid = threadIdx.x;
  const int bid = blockIdx.x;
  const int swzb = ((bid & 7) << 6) | (bid >> 3);     // XCD-cluster swizzle
  const int b = swzb >> 5;
  const int itile = (swzb & 31) << 5;

  // ---- stage dst, src (pre-scaled by log2e so exp(x) -> exp2(x')) ----
  for (int idx = tid; idx < 4096; idx += 256)
    sDst[idx] = dstp[(size_t)b * 4096 + idx] * LOG2E;
  if (tid < 128)
    sSrc[tid] = srcp[((size_t)b * 1024 + itile) * 4 + tid] * LOG2E;

  // ---- build adj bitmask ----
  {
    const int row = tid >> 3;
    const int w0 = (tid & 7) << 2;
    const int* arow_g = adj + (size_t)(itile + row) * 1024 + (w0 << 5);
#pragma unroll
    for (int wq = 0; wq < 4; ++wq) {
      unsigned int word = 0;
#pragma unroll
      for (int c4 = 0; c4 < 8; ++c4) {
        int4 v = *reinterpret_cast<const int4*>(arow_g + (wq << 5) + (c4 << 2));
        word |= (unsigned)((v.x != 0) ? 1 : 0) << (c4 * 4 + 0);
        word |= (unsigned)((v.y != 0) ? 1 : 0) << (c4 * 4 + 1);
        word |= (unsigned)((v.z != 0) ? 1 : 0) << (c4 * 4 + 2);
        word |= (unsigned)((v.w != 0) ? 1 : 0) << (c4 * 4 + 3);
      }
      sAdjW[row][w0 + wq] = word;
    }
  }
  __syncthreads();

  // ---- pass 1: row sums (m=0 softmax; logits bounded) ----
  {
    const int i = tid >> 3;
    const int par = tid & 7;
    const float4 sv = *reinterpret_cast<const float4*>(&sSrc[i * 4]);
    f32x4 acc = (f32x4){0.f, 0.f, 0.f, 0.f};
    const unsigned int bit0 = 1u << par;
    for (int kw = 0; kw < 32; ++kw) {
      const unsigned int word = sAdjW[i][kw];
#pragma unroll
      for (int e = 0; e < 4; ++e) {
        const int gj = (kw << 5) + (e << 3) + par;
        const float4 dv = *reinterpret_cast<const float4*>(&sDst[gj * 4]);
        const float mf = (word & (bit0 << (e << 3))) ? 1.0f : 0.0f;
        acc[0] = fmaf(mf, exp2_fast(leaky02(sv.x + dv.x)), acc[0]);
        acc[1] = fmaf(mf, exp2_fast(leaky02(sv.y + dv.y)), acc[1]);
        acc[2] = fmaf(mf, exp2_fast(leaky02(sv.z + dv.z)), acc[2]);
        acc[3] = fmaf(mf, exp2_fast(leaky02(sv.w + dv.w)), acc[3]);
      }
    }
#pragma unroll
    for (int m = 1; m < 8; m <<= 1) {
#pragma unroll
      for (int q = 0; q < 4; ++q) acc[q] += __shfl_xor(acc[q], m, 64);
    }
    if (par == 0) {
      float4 isv;
      isv.x = acc[0] > 0.f ? rcp_fast(acc[0]) : -1.0f;
      isv.y = acc[1] > 0.f ? rcp_fast(acc[1]) : -1.0f;
      isv.z = acc[2] > 0.f ? rcp_fast(acc[2]) : -1.0f;
      isv.w = acc[3] > 0.f ? rcp_fast(acc[3]) : -1.0f;
      *reinterpret_cast<float4*>(&sIS[i * 4]) = isv;
    }
  }
  __syncthreads();

  // ---- pass 2: 32 j-tiles of 32, single barrier per tile (dbuf) ----
  const int il = tid >> 3;          // 0..31 (i row)
  const int jsub = tid & 7;         // stride-8 j within tile (coalesced)
  const int wv = tid >> 6;          // wave id = head for MFMA phase
  const int l = tid & 63;
  const int jjB = tid & 31;         // B-staging: Wh row within tile
  const int fcB = tid >> 5;         // B-staging: 16-hf chunk

  const float4 sv4 = *reinterpret_cast<const float4*>(&sSrc[il * 4]);
  const float4 is4 = *reinterpret_cast<const float4*>(&sIS[il * 4]);
  f32x4* arow_out = reinterpret_cast<f32x4*>(
      attn_out + ((size_t)(b * 1024 + itile + il)) * 4096);

  f32x4 accg[2][2];
#pragma unroll
  for (int m = 0; m < 2; ++m)
#pragma unroll
    for (int n = 0; n < 2; ++n) accg[m][n] = (f32x4){0.f, 0.f, 0.f, 0.f};

  const int frow = l & 15, fchunk = l >> 4;

  for (int jt = 0; jt < 32; ++jt) {
    const int j0 = jt << 5;
    const int cur = jt & 1;
    // -- stage & write phase (overlaps other waves' MFMA of jt-1) --
    {
      const unsigned int word = sAdjW[il][jt];
#pragma unroll
      for (int q = 0; q < 4; ++q) {
        const int j = jsub + (q << 3);
        const int gj = j0 + j;
        const float4 dv = *reinterpret_cast<const float4*>(&sDst[gj * 4]);
        const float mf = (word & (1u << j)) ? 1.0f : 0.0f;
        f32x4 a4;
        float ex;
        ex = mf * exp2_fast(leaky02(sv4.x + dv.x)); a4[0] = ex * is4.x; if (is4.x < 0.f) a4[0] = 9.765625e-4f;
        ex = mf * exp2_fast(leaky02(sv4.y + dv.y)); a4[1] = ex * is4.y; if (is4.y < 0.f) a4[1] = 9.765625e-4f;
        ex = mf * exp2_fast(leaky02(sv4.z + dv.z)); a4[2] = ex * is4.z; if (is4.z < 0.f) a4[2] = 9.765625e-4f;
        ex = mf * exp2_fast(leaky02(sv4.w + dv.w)); a4[3] = ex * is4.w; if (is4.w < 0.f) a4[3] = 9.765625e-4f;
        __builtin_nontemporal_store(a4, &arow_out[gj]);
        sP[cur][0][il][j] = (_Float16)a4[0];
        sP[cur][1][il][j] = (_Float16)a4[1];
        sP[cur][2][il][j] = (_Float16)a4[2];
        sP[cur][3][il][j] = (_Float16)a4[3];
      }
      // B staging: Wh[j0+jjB][fcB*16..+16] -> sB[cur][h][f][jjB]
      const float* wrow = Wh + ((size_t)(b * 1024 + j0 + jjB)) * 128 + (fcB << 4);
#pragma unroll
      for (int c4 = 0; c4 < 4; ++c4) {
        float4 v = *reinterpret_cast<const float4*>(wrow + (c4 << 2));
        float vv[4] = {v.x, v.y, v.z, v.w};
#pragma unroll
        for (int e = 0; e < 4; ++e) {
          const int hf = (fcB << 4) + (c4 << 2) + e;
          sB[cur][hf >> 5][hf & 31][jjB] = (_Float16)vv[e];
        }
      }
    }
    __syncthreads();
    // -- MFMA phase: wave wv handles head wv (4 MF16) --
    {
      half8 pa[2], wb[2];
#pragma unroll
      for (int m = 0; m < 2; ++m)
        pa[m] = *reinterpret_cast<const half8*>(&sP[cur][wv][m * 16 + frow][fchunk << 3]);
#pragma unroll
      for (int n = 0; n < 2; ++n)
        wb[n] = *reinterpret_cast<const half8*>(&sB[cur][wv][n * 16 + frow][fchunk << 3]);
#pragma unroll
      for (int m = 0; m < 2; ++m)
#pragma unroll
        for (int n = 0; n < 2; ++n)
          accg[m][n] = MF16(pa[m], wb[n], accg[m][n]);
    }
  }

  // ---- epilogue: elu + store gat ----
#pragma unroll
  for (int m = 0; m < 2; ++m)
#pragma unroll
    for (int n = 0; n < 2; ++n)
#pragma unroll
      for (int q = 0; q < 4; ++q) {
        const int i = m * 16 + (l >> 4) * 4 + q;
        const int f = n * 16 + (l & 15);
        float v = accg[m][n][q];
        v = v > 0.0f ? v : (exp2_fast(v * LOG2E) - 1.0f);
        gat_out[((size_t)(b * 1024 + itile + i)) * 128 + wv * 32 + f] = v;
      }
}

// ---------------------------------------------------------------------------
// MLP chain (tanh via exp2/rcp).
// ---------------------------------------------------------------------------
__global__ __launch_bounds__(256) void mlp_kernel(
    const float* __restrict__ gat,
    const float* __restrict__ rW1, const float* __restrict__ rb1,
    const float* __restrict__ rW2, const float* __restrict__ rb2,
    const float* __restrict__ fW,  const float* __restrict__ fb,
    const float* __restrict__ ln_g, const float* __restrict__ ln_b,
    const float* __restrict__ nW1, const float* __restrict__ nb1,
    const float* __restrict__ nW2, const float* __restrict__ nb2,
    float* __restrict__ out)
{
  __shared__ float sW[128 * 128];
  __shared__ float sZ[16][128];
  __shared__ float sT[16][128];
  __shared__ float sY[16][32];
  __shared__ float sT2[16][32];
  __shared__ float sB1[128], sB2[128];

  const int tid = threadIdx.x;
  const int rowbase = blockIdx.x * 16;

  for (int idx = tid; idx < 16384; idx += 256) sW[idx] = rW1[idx];
  if (tid < 128) { sB1[tid] = rb1[tid]; sB2[tid] = rb2[tid]; }
  for (int idx = tid; idx < 2048; idx += 256)
    sZ[idx >> 7][idx & 127] = gat[(size_t)rowbase * 128 + idx];
  __syncthreads();

  const int c = tid & 127, rblk = tid >> 7;
  for (int q = 0; q < 8; ++q) {
    const int r = rblk + (q << 1);
    float a = sB1[c];
#pragma unroll 8
    for (int k = 0; k < 128; ++k) a = fmaf(sZ[r][k], sW[k * 128 + c], a);
    sT[r][c] = a > 0.0f ? a : 0.0f;
  }
  __syncthreads();
  for (int idx = tid; idx < 16384; idx += 256) sW[idx] = rW2[idx];
  __syncthreads();
  for (int q = 0; q < 8; ++q) {
    const int r = rblk + (q << 1);
    float a = sB2[c];
#pragma unroll 8
    for (int k = 0; k < 128; ++k) a = fmaf(sT[r][k], sW[k * 128 + c], a);
    a += sZ[r][c];
    sZ[r][c] = a > 0.0f ? a : 0.0f;
  }
  __syncthreads();
  for (int idx = tid; idx < 4096; idx += 256) sW[idx] = fW[idx];
  for (int idx = tid; idx < 1024; idx += 256) {
    sW[4096 + idx] = nW1[idx];
    sW[5120 + idx] = nW2[idx];
  }
  if (tid < 32) {
    sW[6144 + tid] = fb[tid];
    sW[6176 + tid] = ln_g[tid];
    sW[6208 + tid] = ln_b[tid];
    sW[6240 + tid] = nb1[tid];
    sW[6272 + tid] = nb2[tid];
  }
  __syncthreads();

  const int o = tid & 31, rr2 = tid >> 5;
  for (int g = 0; g < 2; ++g) {
    const int r = rr2 + (g << 3);
    float y = sW[6144 + o];
#pragma unroll 8
    for (int k = 0; k < 128; ++k) y = fmaf(sZ[r][k], sW[k * 32 + o], y);
    float mu = y;
#pragma unroll
    for (int m = 16; m >= 1; m >>= 1) mu += __shfl_xor(mu, m, 32);
    mu *= (1.0f / 32.0f);
    const float d = y - mu;
    float var = d * d;
#pragma unroll
    for (int m = 16; m >= 1; m >>= 1) var += __shfl_xor(var, m, 32);
    var *= (1.0f / 32.0f);
    const float yn = d * rsqrtf(var + 1e-5f) * sW[6176 + o] + sW[6208 + o];
    sY[r][o] = tanh_e(yn);
  }
  __syncthreads();
  for (int g = 0; g < 2; ++g) {
    const int r = rr2 + (g << 3);
    float a = sW[6240 + o];
#pragma unroll
    for (int k = 0; k < 32; ++k) a = fmaf(sY[r][k], sW[4096 + k * 32 + o], a);
    sT2[r][o] = a > 0.0f ? a : 0.0f;
  }
  __syncthreads();
  for (int g = 0; g < 2; ++g) {
    const int r = rr2 + (g << 3);
    float a = sW[6272 + o];
#pragma unroll
    for (int k = 0; k < 32; ++k) a = fmaf(sT2[r][k], sW[5120 + k * 32 + o], a);
    out[(size_t)(rowbase + r) * 32 + o] = a;
  }
}

// ---------------------------------------------------------------------------
extern "C" void kernel_launch(void* const* d_in, const int* in_sizes, int n_in,
                              void* d_out, int out_size, void* d_ws, size_t ws_size,
                              hipStream_t stream) {
  const float* seq   = (const float*)d_in[0];
  const int*   adj   = (const int*)d_in[1];
  const float* Wih0  = (const float*)d_in[2];
  const float* Whh0  = (const float*)d_in[3];
  const float* bih0  = (const float*)d_in[4];
  const float* bhh0  = (const float*)d_in[5];
  const float* Wih1  = (const float*)d_in[6];
  const float* Whh1  = (const float*)d_in[7];
  const float* bih1  = (const float*)d_in[8];
  const float* bhh1  = (const float*)d_in[9];
  const float* gatW  = (const float*)d_in[10];
  const float* a_src = (const float*)d_in[11];
  const float* a_dst = (const float*)d_in[12];
  const float* rW1   = (const float*)d_in[13];
  const float* rb1   = (const float*)d_in[14];
  const float* rW2   = (const float*)d_in[15];
  const float* rb2   = (const float*)d_in[16];
  const float* fW    = (const float*)d_in[17];
  const float* fb    = (const float*)d_in[18];
  const float* ln_g  = (const float*)d_in[19];
  const float* ln_b  = (const float*)d_in[20];
  const float* nW1   = (const float*)d_in[21];
  const float* nb1   = (const float*)d_in[22];
  const float* nW2   = (const float*)d_in[23];
  const float* nb2   = (const float*)d_in[24];

  float* out  = (float*)d_out;                  // [BN][32] at offset 0
  float* attn = out + (size_t)BN * OO;          // [B,N,N,4] region (268MB)

  float* ws   = (float*)d_ws;
  float* Wh   = ws;                             // [BN][128]
  float* srcv = Wh + (size_t)BN * 128;          // [BN][4]
  float* dstv = srcv + (size_t)BN * 4;          // [BN][4]
  float* gat  = dstv + (size_t)BN * 4;          // [BN][128]

  gru_fused_kernel<<<512, 512, 0, stream>>>(seq, Wih0, Whh0, bih0, bhh0,
                                            Wih1, Whh1, bih1, bhh1,
                                            gatW, a_src, a_dst, Wh, srcv, dstv);
  attn_kernel<<<512, 256, 0, stream>>>(Wh, srcv, dstv, adj, attn, gat);
  mlp_kernel<<<1024, 256, 0, stream>>>(gat, rW1, rb1, rW2, rb2, fW, fb,
                                       ln_g, ln_b, nW1, nb1, nW2, nb2, out);
}

// Round 19
// 184.535 us; speedup vs baseline: 1.6458x; 1.5169x over previous
//
#include <hip/hip_runtime.h>

// Problem constants
#define BB 16
#define TT 32
#define NN 1024
#define DD 64
#define HH 64
#define BN 16384          // B*N
#define GH 128
#define RR 128
#define OO 32

#define LOG2E 1.44269504088896f

typedef __attribute__((ext_vector_type(8))) short short8;
typedef __attribute__((ext_vector_type(4))) float f32x4;
typedef __attribute__((ext_vector_type(8))) _Float16 half8;
typedef __attribute__((ext_vector_type(2))) __fp16 fp16x2;

#define MF16(A, B, C) __builtin_amdgcn_mfma_f32_16x16x32_f16((A), (B), (C), 0, 0, 0)

__device__ __forceinline__ float rcp_fast(float x) {
  return __builtin_amdgcn_rcpf(x);
}
__device__ __forceinline__ float exp2_fast(float x) {
  return __builtin_amdgcn_exp2f(x);
}
__device__ __forceinline__ float sigmoid2(float a) {   // a = x*log2e
  return rcp_fast(1.0f + exp2_fast(-a));
}
__device__ __forceinline__ float tanh2(float a) {      // a = x*log2e
  return fmaf(-2.0f, rcp_fast(exp2_fast(2.0f * a) + 1.0f), 1.0f);
}
__device__ __forceinline__ float tanh_e(float x) {
  return tanh2(x * LOG2E);
}
__device__ __forceinline__ float leaky02(float x) {
  return fmaxf(x, 0.2f * x);
}

// ---------------------------------------------------------------------------
// Fused 2-layer GRU + GAT projection, v9 (unchanged from R18).
// ---------------------------------------------------------------------------
__global__ __launch_bounds__(512, 4) void gru_fused_kernel(
    const float* __restrict__ x,
    const float* __restrict__ Wih0, const float* __restrict__ Whh0,
    const float* __restrict__ bih0, const float* __restrict__ bhh0,
    const float* __restrict__ Wih1, const float* __restrict__ Whh1,
    const float* __restrict__ bih1, const float* __restrict__ bhh1,
    const float* __restrict__ gatW, const float* __restrict__ a_src,
    const float* __restrict__ a_dst,
    float* __restrict__ Wh, float* __restrict__ srcv, float* __restrict__ dstv)
{
  __shared__ _Float16 sX[2][2048];     // [buf][seq*64 + swz(k)] : 8 KB
  __shared__ _Float16 sH0[2][2048];    // 8 KB
  __shared__ _Float16 sH1[2][2048];    // 8 KB

  const int tid = threadIdx.x;
  const int gbase = blockIdx.x * 32;

  const int w = tid >> 6, l = tid & 63;
  const int layer = w >> 2;            // 0 or 1
  const int jt = w & 3;                // 16-col j-group
  const int c = l & 15;                // D col (j) / A row within M-tile
  const int rq = l >> 4;               // A k-chunk / D row-group

  const float* Wih = layer ? Wih1 : Wih0;
  const float* Whh = layer ? Whh1 : Whh0;
  const float* bihp = layer ? bih1 : bih0;
  const float* bhhp = layer ? bhh1 : bhh0;

  // ---- weight fragments: global -> reg, fp16 single-plane, x log2e ----
  half8 wf[3][2][2];
#pragma unroll
  for (int g = 0; g < 3; ++g) {
    const int row = g * 64 + jt * 16 + c;
#pragma unroll
    for (int ks = 0; ks < 2; ++ks) {
      const int col = ks * 32 + (rq << 3);
      float4 i0 = *reinterpret_cast<const float4*>(Wih + row * 64 + col);
      float4 i1 = *reinterpret_cast<const float4*>(Wih + row * 64 + col + 4);
      float4 h0 = *reinterpret_cast<const float4*>(Whh + row * 64 + col);
      float4 h1 = *reinterpret_cast<const float4*>(Whh + row * 64 + col + 4);
      float wi[8] = {i0.x, i0.y, i0.z, i0.w, i1.x, i1.y, i1.z, i1.w};
      float wh[8] = {h0.x, h0.y, h0.z, h0.w, h1.x, h1.y, h1.z, h1.w};
      half8 vih, vhh;
#pragma unroll
      for (int e = 0; e < 8; ++e) {
        vih[e] = (_Float16)(wi[e] * LOG2E);
        vhh[e] = (_Float16)(wh[e] * LOG2E);
      }
      wf[g][0][ks] = vih;
      wf[g][1][ks] = vhh;
    }
  }

  // ---- X staging role: thread -> (seq = tid>>4 (0..31), k4 = (tid&15)*4) ----
  const int sseq = tid >> 4;
  const int kq = (tid & 15) << 2;
  const float* xrow = x + (size_t)(gbase + sseq) * (TT * 64) + kq;
  const int sxoff = sseq * 64 + (kq ^ ((sseq & 7) << 3));  // 4-chunk stays contiguous

  // zero-init H buffers read at first active steps
  for (int i = tid; i < 2048; i += 512) {
    sH0[0][i] = (_Float16)0.0f;
    sH1[0][i] = (_Float16)0.0f;
  }

  // prologue: stage X(0); preload X(1)
  float4 p = *reinterpret_cast<const float4*>(xrow);
  *reinterpret_cast<fp16x2*>(&sX[0][sxoff])     = __builtin_amdgcn_cvt_pkrtz(p.x, p.y);
  *reinterpret_cast<fp16x2*>(&sX[0][sxoff + 2]) = __builtin_amdgcn_cvt_pkrtz(p.z, p.w);
  p = *reinterpret_cast<const float4*>(xrow + 64);

  // biases for this thread's j column (x log2e)
  const int jj = jt * 16 + c;
  const float br  = (bihp[jj]       + bhhp[jj])      * LOG2E;
  const float bz  = (bihp[64 + jj]  + bhhp[64 + jj]) * LOG2E;
  const float bni = bihp[128 + jj] * LOG2E;
  const float bnh = bhhp[128 + jj] * LOG2E;

  // A-frag offsets for 2 M-tiles; (mi*16+c)&7 == c&7, swizzle invariant
  int ao[2][2];
#pragma unroll
  for (int mi = 0; mi < 2; ++mi)
#pragma unroll
    for (int ks = 0; ks < 2; ++ks)
      ao[mi][ks] = (mi * 16 + c) * 64 + (((ks << 5) + (rq << 3)) ^ ((c & 7) << 3));
  int hoff[2][4];
#pragma unroll
  for (int mi = 0; mi < 2; ++mi)
#pragma unroll
    for (int q = 0; q < 4; ++q) {
      const int seq = mi * 16 + (rq << 2) + q;
      hoff[mi][q] = seq * 64 + (jj ^ ((seq & 7) << 3));
    }

  float h[2][4];
#pragma unroll
  for (int mi = 0; mi < 2; ++mi)
#pragma unroll
    for (int q = 0; q < 4; ++q) h[mi][q] = 0.0f;

  for (int t = 0; t <= TT; ++t) {
    __syncthreads();
    const int cb = t & 1, nb = cb ^ 1;
    if (t + 1 < TT) {
      *reinterpret_cast<fp16x2*>(&sX[nb][sxoff])     = __builtin_amdgcn_cvt_pkrtz(p.x, p.y);
      *reinterpret_cast<fp16x2*>(&sX[nb][sxoff + 2]) = __builtin_amdgcn_cvt_pkrtz(p.z, p.w);
    }
    if (t + 2 < TT)
      p = *reinterpret_cast<const float4*>(xrow + (t + 2) * 64);

    const bool active = layer ? (t >= 1) : (t < TT);
    if (active) {
      const _Float16* xsrc = layer ? &sH0[cb][0] : &sX[cb][0];
      const _Float16* hsrc = layer ? &sH1[nb][0] : &sH0[cb][0];
      _Float16* hdst       = layer ? &sH1[cb][0] : &sH0[nb][0];

      f32x4 accr[2], accz[2], accni[2], accnh[2];
#pragma unroll
      for (int mi = 0; mi < 2; ++mi) {
        accr[mi]  = (f32x4){br, br, br, br};
        accz[mi]  = (f32x4){bz, bz, bz, bz};
        accni[mi] = (f32x4){bni, bni, bni, bni};
        accnh[mi] = (f32x4){bnh, bnh, bnh, bnh};
      }

#pragma unroll
      for (int ks = 0; ks < 2; ++ks) {
#pragma unroll
        for (int mi = 0; mi < 2; ++mi) {
          const half8 xa = *reinterpret_cast<const half8*>(xsrc + ao[mi][ks]);
          const half8 ha = *reinterpret_cast<const half8*>(hsrc + ao[mi][ks]);
          accr[mi]  = MF16(xa, wf[0][0][ks], accr[mi]);
          accr[mi]  = MF16(ha, wf[0][1][ks], accr[mi]);
          accz[mi]  = MF16(xa, wf[1][0][ks], accz[mi]);
          accz[mi]  = MF16(ha, wf[1][1][ks], accz[mi]);
          accni[mi] = MF16(xa, wf[2][0][ks], accni[mi]);
          accnh[mi] = MF16(ha, wf[2][1][ks], accnh[mi]);
        }
      }

#pragma unroll
      for (int mi = 0; mi < 2; ++mi)
#pragma unroll
        for (int q = 0; q < 4; ++q) {
          float rg = sigmoid2(accr[mi][q]);
          float zg = sigmoid2(accz[mi][q]);
          float ng = tanh2(fmaf(rg, accnh[mi][q], accni[mi][q]));
          float hv = fmaf(zg, h[mi][q] - ng, ng);   // n + z*(h-n)
          h[mi][q] = hv;
          hdst[hoff[mi][q]] = (_Float16)hv;
        }
    }
  }

  // ---- fused GAT projection epilogue: Wh = h1 @ gatW (+ src/dst) ----
  __syncthreads();   // all sH1[0] writes visible
  float* sRed = reinterpret_cast<float*>(&sX[0][0]);  // reuse: 512 floats used
  {
    const int col = (w << 4) + c;     // hf column 0..127 (wave w = 16-col group)
    half8 gb[2];
#pragma unroll
    for (int ks = 0; ks < 2; ++ks)
#pragma unroll
      for (int e = 0; e < 8; ++e) {
        const int k = ks * 32 + (rq << 3) + e;
        gb[ks][e] = (_Float16)gatW[k * 128 + col];
      }
    const float as = a_src[col], ad = a_dst[col];
    f32x4 accw[2];
#pragma unroll
    for (int mi = 0; mi < 2; ++mi) {
      accw[mi] = (f32x4){0.f, 0.f, 0.f, 0.f};
#pragma unroll
      for (int ks = 0; ks < 2; ++ks) {
        const half8 fa = *reinterpret_cast<const half8*>(&sH1[0][0] + ao[mi][ks]);
        accw[mi] = MF16(fa, gb[ks], accw[mi]);
      }
    }
#pragma unroll
    for (int mi = 0; mi < 2; ++mi)
#pragma unroll
      for (int q = 0; q < 4; ++q) {
        const int seq = mi * 16 + (rq << 2) + q;
        Wh[(size_t)(gbase + seq) * 128 + col] = accw[mi][q];
        float s = accw[mi][q] * as, d = accw[mi][q] * ad;
#pragma unroll
        for (int mm = 1; mm < 16; mm <<= 1) {
          s += __shfl_xor(s, mm, 64);
          d += __shfl_xor(d, mm, 64);
        }
        if (c == 0) {
          sRed[w * 32 + seq]       = s;
          sRed[256 + w * 32 + seq] = d;
        }
      }
  }
  __syncthreads();
  if (tid < 256) {
    const int hh = tid >> 6;          // head 0..3
    const int rem = tid & 63;
    const int sd = rem >> 5;          // 0 = src, 1 = dst
    const int ii = rem & 31;
    const float v = sRed[sd * 256 + (hh * 2) * 32 + ii] +
                    sRed[sd * 256 + (hh * 2 + 1) * 32 + ii];
    float* outp = sd ? dstv : srcv;
    outp[(size_t)(gbase + ii) * 4 + hh] = v;
  }
}

// ---------------------------------------------------------------------------
// Attention + gat aggregation, v5 (unchanged from R15).
// ---------------------------------------------------------------------------
__global__ __launch_bounds__(256) void attn_kernel(
    const float* __restrict__ Wh, const float* __restrict__ srcp,
    const float* __restrict__ dstp, const int* __restrict__ adj,
    float* __restrict__ attn_out, float* __restrict__ gat_out)
{
  __shared__ __align__(16) float sDst[4096];          // 16 KB (x log2e)
  __shared__ __align__(16) float sSrc[128];           // (x log2e)
  __shared__ __align__(16) float sIS[128];            // 1/sum (or -1 sentinel)
  __shared__ unsigned int sAdjW[32][32];              // 4 KB bitmask
  __shared__ __align__(16) _Float16 sP[2][4][32][40]; // [buf][h][i][j] 20 KB
  __shared__ __align__(16) _Float16 sB[2][4][32][40]; // [buf][h][f][j] 20 KB

  const int tid = threadIdx.x;
  const int bid = blockIdx.x;
  const int swzb = ((bid & 7) << 6) | (bid >> 3);     // XCD-cluster swizzle
  const int b = swzb >> 5;
  const int itile = (swzb & 31) << 5;

  for (int idx = tid; idx < 4096; idx += 256)
    sDst[idx] = dstp[(size_t)b * 4096 + idx] * LOG2E;
  if (tid < 128)
    sSrc[tid] = srcp[((size_t)b * 1024 + itile) * 4 + tid] * LOG2E;

  {
    const int row = tid >> 3;
    const int w0 = (tid & 7) << 2;
    const int* arow_g = adj + (size_t)(itile + row) * 1024 + (w0 << 5);
#pragma unroll
    for (int wq = 0; wq < 4; ++wq) {
      unsigned int word = 0;
#pragma unroll
      for (int c4 = 0; c4 < 8; ++c4) {
        int4 v = *reinterpret_cast<const int4*>(arow_g + (wq << 5) + (c4 << 2));
        word |= (unsigned)((v.x != 0) ? 1 : 0) << (c4 * 4 + 0);
        word |= (unsigned)((v.y != 0) ? 1 : 0) << (c4 * 4 + 1);
        word |= (unsigned)((v.z != 0) ? 1 : 0) << (c4 * 4 + 2);
        word |= (unsigned)((v.w != 0) ? 1 : 0) << (c4 * 4 + 3);
      }
      sAdjW[row][w0 + wq] = word;
    }
  }
  __syncthreads();

  {
    const int i = tid >> 3;
    const int par = tid & 7;
    const float4 sv = *reinterpret_cast<const float4*>(&sSrc[i * 4]);
    f32x4 acc = (f32x4){0.f, 0.f, 0.f, 0.f};
    const unsigned int bit0 = 1u << par;
    for (int kw = 0; kw < 32; ++kw) {
      const unsigned int word = sAdjW[i][kw];
#pragma unroll
      for (int e = 0; e < 4; ++e) {
        const int gj = (kw << 5) + (e << 3) + par;
        const float4 dv = *reinterpret_cast<const float4*>(&sDst[gj * 4]);
        const float mf = (word & (bit0 << (e << 3))) ? 1.0f : 0.0f;
        acc[0] = fmaf(mf, exp2_fast(leaky02(sv.x + dv.x)), acc[0]);
        acc[1] = fmaf(mf, exp2_fast(leaky02(sv.y + dv.y)), acc[1]);
        acc[2] = fmaf(mf, exp2_fast(leaky02(sv.z + dv.z)), acc[2]);
        acc[3] = fmaf(mf, exp2_fast(leaky02(sv.w + dv.w)), acc[3]);
      }
    }
#pragma unroll
    for (int m = 1; m < 8; m <<= 1) {
#pragma unroll
      for (int q = 0; q < 4; ++q) acc[q] += __shfl_xor(acc[q], m, 64);
    }
    if (par == 0) {
      float4 isv;
      isv.x = acc[0] > 0.f ? rcp_fast(acc[0]) : -1.0f;
      isv.y = acc[1] > 0.f ? rcp_fast(acc[1]) : -1.0f;
      isv.z = acc[2] > 0.f ? rcp_fast(acc[2]) : -1.0f;
      isv.w = acc[3] > 0.f ? rcp_fast(acc[3]) : -1.0f;
      *reinterpret_cast<float4*>(&sIS[i * 4]) = isv;
    }
  }
  __syncthreads();

  const int il = tid >> 3;
  const int jsub = tid & 7;
  const int wv = tid >> 6;
  const int l = tid & 63;
  const int jjB = tid & 31;
  const int fcB = tid >> 5;

  const float4 sv4 = *reinterpret_cast<const float4*>(&sSrc[il * 4]);
  const float4 is4 = *reinterpret_cast<const float4*>(&sIS[il * 4]);
  f32x4* arow_out = reinterpret_cast<f32x4*>(
      attn_out + ((size_t)(b * 1024 + itile + il)) * 4096);

  f32x4 accg[2][2];
#pragma unroll
  for (int m = 0; m < 2; ++m)
#pragma unroll
    for (int n = 0; n < 2; ++n) accg[m][n] = (f32x4){0.f, 0.f, 0.f, 0.f};

  const int frow = l & 15, fchunk = l >> 4;

  for (int jt = 0; jt < 32; ++jt) {
    const int j0 = jt << 5;
    const int cur = jt & 1;
    {
      const unsigned int word = sAdjW[il][jt];
#pragma unroll
      for (int q = 0; q < 4; ++q) {
        const int j = jsub + (q << 3);
        const int gj = j0 + j;
        const float4 dv = *reinterpret_cast<const float4*>(&sDst[gj * 4]);
        const float mf = (word & (1u << j)) ? 1.0f : 0.0f;
        f32x4 a4;
        float ex;
        ex = mf * exp2_fast(leaky02(sv4.x + dv.x)); a4[0] = ex * is4.x; if (is4.x < 0.f) a4[0] = 9.765625e-4f;
        ex = mf * exp2_fast(leaky02(sv4.y + dv.y)); a4[1] = ex * is4.y; if (is4.y < 0.f) a4[1] = 9.765625e-4f;
        ex = mf * exp2_fast(leaky02(sv4.z + dv.z)); a4[2] = ex * is4.z; if (is4.z < 0.f) a4[2] = 9.765625e-4f;
        ex = mf * exp2_fast(leaky02(sv4.w + dv.w)); a4[3] = ex * is4.w; if (is4.w < 0.f) a4[3] = 9.765625e-4f;
        __builtin_nontemporal_store(a4, &arow_out[gj]);
        sP[cur][0][il][j] = (_Float16)a4[0];
        sP[cur][1][il][j] = (_Float16)a4[1];
        sP[cur][2][il][j] = (_Float16)a4[2];
        sP[cur][3][il][j] = (_Float16)a4[3];
      }
      const float* wrow = Wh + ((size_t)(b * 1024 + j0 + jjB)) * 128 + (fcB << 4);
#pragma unroll
      for (int c4 = 0; c4 < 4; ++c4) {
        float4 v = *reinterpret_cast<const float4*>(wrow + (c4 << 2));
        float vv[4] = {v.x, v.y, v.z, v.w};
#pragma unroll
        for (int e = 0; e < 4; ++e) {
          const int hf = (fcB << 4) + (c4 << 2) + e;
          sB[cur][hf >> 5][hf & 31][jjB] = (_Float16)vv[e];
        }
      }
    }
    __syncthreads();
    {
      half8 pa[2], wb[2];
#pragma unroll
      for (int m = 0; m < 2; ++m)
        pa[m] = *reinterpret_cast<const half8*>(&sP[cur][wv][m * 16 + frow][fchunk << 3]);
#pragma unroll
      for (int n = 0; n < 2; ++n)
        wb[n] = *reinterpret_cast<const half8*>(&sB[cur][wv][n * 16 + frow][fchunk << 3]);
#pragma unroll
      for (int m = 0; m < 2; ++m)
#pragma unroll
        for (int n = 0; n < 2; ++n)
          accg[m][n] = MF16(pa[m], wb[n], accg[m][n]);
    }
  }

#pragma unroll
  for (int m = 0; m < 2; ++m)
#pragma unroll
    for (int n = 0; n < 2; ++n)
#pragma unroll
      for (int q = 0; q < 4; ++q) {
        const int i = m * 16 + (l >> 4) * 4 + q;
        const int f = n * 16 + (l & 15);
        float v = accg[m][n][q];
        v = v > 0.0f ? v : (exp2_fast(v * LOG2E) - 1.0f);
        gat_out[((size_t)(b * 1024 + itile + i)) * 128 + wv * 32 + f] = v;
      }
}

// ---------------------------------------------------------------------------
// MLP chain, v2: 32 rows/block (512 blocks). Phases 1-2 (84% of FLOPs) via
// fp16 MFMA with the GRU-validated swizzled A/B LDS fragment layout; the
// residual z re-read from global in fp32. Phases 3-5 (32-col, small) keep
// the scalar path with LDS reuse. LDS 64 KB -> 2 blocks/CU.
// ---------------------------------------------------------------------------
__global__ __launch_bounds__(256) void mlp_kernel(
    const float* __restrict__ gat,
    const float* __restrict__ rW1, const float* __restrict__ rb1,
    const float* __restrict__ rW2, const float* __restrict__ rb2,
    const float* __restrict__ fW,  const float* __restrict__ fb,
    const float* __restrict__ ln_g, const float* __restrict__ ln_b,
    const float* __restrict__ nW1, const float* __restrict__ nb1,
    const float* __restrict__ nW2, const float* __restrict__ nb2,
    float* __restrict__ out)
{
  __shared__ __align__(16) _Float16 zA[32 * 128];   // 8 KB  A-plane (swz)
  __shared__ __align__(16) _Float16 wB[128 * 128];  // 32 KB B-plane (swz) / fp32 reuse
  __shared__ __align__(16) _Float16 tA[32 * 128];   // 8 KB  A-plane (swz)
  __shared__ __align__(16) float    sR[32 * 128];   // 16 KB res fp32

  const int tid = threadIdx.x;
  const int rowbase = blockIdx.x * 32;

  // ---- stage z = gat rows -> zA fp16 swizzled (k ^ ((row&7)<<3)) ----
  for (int idx = tid; idx < 1024; idx += 256) {
    const int row = idx >> 5, k4 = (idx & 31) << 2;
    float4 v = *reinterpret_cast<const float4*>(gat + (size_t)(rowbase + row) * 128 + k4);
    const int off = row * 128 + (k4 ^ ((row & 7) << 3));
    *reinterpret_cast<fp16x2*>(&zA[off])     = __builtin_amdgcn_cvt_pkrtz(v.x, v.y);
    *reinterpret_cast<fp16x2*>(&zA[off + 2]) = __builtin_amdgcn_cvt_pkrtz(v.z, v.w);
  }
  // ---- stage rW1^T -> wB fp16 (wB[n][k] = rW1[k][n]); lanes consecutive in n ----
  for (int idx = tid; idx < 2048; idx += 256) {
    const int n = idx & 127, kc = (idx >> 7) << 3;
    half8 hv;
#pragma unroll
    for (int e = 0; e < 8; ++e) hv[e] = (_Float16)rW1[(kc + e) * 128 + n];
    *reinterpret_cast<half8*>(&wB[n * 128 + (kc ^ ((n & 7) << 3))]) = hv;
  }
  __syncthreads();

  const int w = tid >> 6, l = tid & 63;
  const int c = l & 15, rq = l >> 4;
  const int n0 = w << 5;               // wave w -> n cols [n0, n0+32)

  int aoz[2][4], bo[2][4];
#pragma unroll
  for (int mi = 0; mi < 2; ++mi)
#pragma unroll
    for (int ks = 0; ks < 4; ++ks)
      aoz[mi][ks] = (mi * 16 + c) * 128 + (((ks << 5) + (rq << 3)) ^ ((c & 7) << 3));
#pragma unroll
  for (int ni = 0; ni < 2; ++ni)
#pragma unroll
    for (int ks = 0; ks < 4; ++ks)
      bo[ni][ks] = (n0 + ni * 16 + c) * 128 + (((ks << 5) + (rq << 3)) ^ ((c & 7) << 3));

  // ---- phase 1: t1 = relu(z @ rW1 + rb1) -> tA fp16 ----
  {
    f32x4 acc[2][2];
#pragma unroll
    for (int ni = 0; ni < 2; ++ni) {
      const float b = rb1[n0 + ni * 16 + c];
#pragma unroll
      for (int mi = 0; mi < 2; ++mi) acc[mi][ni] = (f32x4){b, b, b, b};
    }
#pragma unroll
    for (int ks = 0; ks < 4; ++ks) {
      half8 av[2], bv[2];
#pragma unroll
      for (int mi = 0; mi < 2; ++mi) av[mi] = *reinterpret_cast<const half8*>(&zA[aoz[mi][ks]]);
#pragma unroll
      for (int ni = 0; ni < 2; ++ni) bv[ni] = *reinterpret_cast<const half8*>(&wB[bo[ni][ks]]);
#pragma unroll
      for (int mi = 0; mi < 2; ++mi)
#pragma unroll
        for (int ni = 0; ni < 2; ++ni)
          acc[mi][ni] = MF16(av[mi], bv[ni], acc[mi][ni]);
    }
#pragma unroll
    for (int mi = 0; mi < 2; ++mi)
#pragma unroll
      for (int ni = 0; ni < 2; ++ni)
#pragma unroll
        for (int q = 0; q < 4; ++q) {
          const int row = mi * 16 + (rq << 2) + q;
          const int col = n0 + ni * 16 + c;
          tA[row * 128 + (col ^ ((row & 7) << 3))] = (_Float16)fmaxf(acc[mi][ni][q], 0.0f);
        }
  }
  __syncthreads();
  // ---- stage rW2^T ----
  for (int idx = tid; idx < 2048; idx += 256) {
    const int n = idx & 127, kc = (idx >> 7) << 3;
    half8 hv;
#pragma unroll
    for (int e = 0; e < 8; ++e) hv[e] = (_Float16)rW2[(kc + e) * 128 + n];
    *reinterpret_cast<half8*>(&wB[n * 128 + (kc ^ ((n & 7) << 3))]) = hv;
  }
  __syncthreads();
  // ---- phase 2: res = relu(z + t1 @ rW2 + rb2) -> sR fp32 ----
  {
    f32x4 acc[2][2];
#pragma unroll
    for (int ni = 0; ni < 2; ++ni) {
      const float b = rb2[n0 + ni * 16 + c];
#pragma unroll
      for (int mi = 0; mi < 2; ++mi) acc[mi][ni] = (f32x4){b, b, b, b};
    }
#pragma unroll
    for (int ks = 0; ks < 4; ++ks) {
      half8 av[2], bv[2];
#pragma unroll
      for (int mi = 0; mi < 2; ++mi) av[mi] = *reinterpret_cast<const half8*>(&tA[aoz[mi][ks]]);
#pragma unroll
      for (int ni = 0; ni < 2; ++ni) bv[ni] = *reinterpret_cast<const half8*>(&wB[bo[ni][ks]]);
#pragma unroll
      for (int mi = 0; mi < 2; ++mi)
#pragma unroll
        for (int ni = 0; ni < 2; ++ni)
          acc[mi][ni] = MF16(av[mi], bv[ni], acc[mi][ni]);
    }
#pragma unroll
    for (int mi = 0; mi < 2; ++mi)
#pragma unroll
      for (int ni = 0; ni < 2; ++ni)
#pragma unroll
        for (int q = 0; q < 4; ++q) {
          const int row = mi * 16 + (rq << 2) + q;
          const int col = n0 + ni * 16 + c;
          const float zz = gat[(size_t)(rowbase + row) * 128 + col];
          sR[row * 128 + col] = fmaxf(acc[mi][ni][q] + zz, 0.0f);
        }
  }
  __syncthreads();
  // ---- stage phase 3-5 weights (fp32) into wB region ----
  float* sWf = reinterpret_cast<float*>(&wB[0]);   // 8192 floats available
  for (int idx = tid; idx < 4096; idx += 256) sWf[idx] = fW[idx];
  for (int idx = tid; idx < 1024; idx += 256) {
    sWf[4096 + idx] = nW1[idx];
    sWf[5120 + idx] = nW2[idx];
  }
  if (tid < 32) {
    sWf[6144 + tid] = fb[tid];
    sWf[6176 + tid] = ln_g[tid];
    sWf[6208 + tid] = ln_b[tid];
    sWf[6240 + tid] = nb1[tid];
    sWf[6272 + tid] = nb2[tid];
  }
  __syncthreads();

  float* sY  = reinterpret_cast<float*>(&zA[0]);   // 1024 floats (<= 2048)
  float* sT2 = reinterpret_cast<float*>(&tA[0]);
  const int o = tid & 31, rr2 = tid >> 5;
  // ---- phase 3: y = res @ fW + fb -> LN -> tanh ----
  for (int g = 0; g < 4; ++g) {
    const int r = rr2 + (g << 3);
    float y = sWf[6144 + o];
#pragma unroll 8
    for (int k = 0; k < 128; ++k) y = fmaf(sR[r * 128 + k], sWf[k * 32 + o], y);
    float mu = y;
#pragma unroll
    for (int m = 16; m >= 1; m >>= 1) mu += __shfl_xor(mu, m, 32);
    mu *= (1.0f / 32.0f);
    const float d = y - mu;
    float var = d * d;
#pragma unroll
    for (int m = 16; m >= 1; m >>= 1) var += __shfl_xor(var, m, 32);
    var *= (1.0f / 32.0f);
    const float yn = d * rsqrtf(var + 1e-5f) * sWf[6176 + o] + sWf[6208 + o];
    sY[r * 32 + o] = tanh_e(yn);
  }
  __syncthreads();
  // ---- phase 4: t2 = relu(y @ nW1 + nb1) ----
  for (int g = 0; g < 4; ++g) {
    const int r = rr2 + (g << 3);
    float a = sWf[6240 + o];
#pragma unroll
    for (int k = 0; k < 32; ++k) a = fmaf(sY[r * 32 + k], sWf[4096 + k * 32 + o], a);
    sT2[r * 32 + o] = a > 0.0f ? a : 0.0f;
  }
  __syncthreads();
  // ---- phase 5: out = t2 @ nW2 + nb2 ----
  for (int g = 0; g < 4; ++g) {
    const int r = rr2 + (g << 3);
    float a = sWf[6272 + o];
#pragma unroll
    for (int k = 0; k < 32; ++k) a = fmaf(sT2[r * 32 + k], sWf[5120 + k * 32 + o], a);
    out[(size_t)(rowbase + r) * 32 + o] = a;
  }
}

// ---------------------------------------------------------------------------
extern "C" void kernel_launch(void* const* d_in, const int* in_sizes, int n_in,
                              void* d_out, int out_size, void* d_ws, size_t ws_size,
                              hipStream_t stream) {
  const float* seq   = (const float*)d_in[0];
  const int*   adj   = (const int*)d_in[1];
  const float* Wih0  = (const float*)d_in[2];
  const float* Whh0  = (const float*)d_in[3];
  const float* bih0  = (const float*)d_in[4];
  const float* bhh0  = (const float*)d_in[5];
  const float* Wih1  = (const float*)d_in[6];
  const float* Whh1  = (const float*)d_in[7];
  const float* bih1  = (const float*)d_in[8];
  const float* bhh1  = (const float*)d_in[9];
  const float* gatW  = (const float*)d_in[10];
  const float* a_src = (const float*)d_in[11];
  const float* a_dst = (const float*)d_in[12];
  const float* rW1   = (const float*)d_in[13];
  const float* rb1   = (const float*)d_in[14];
  const float* rW2   = (const float*)d_in[15];
  const float* rb2   = (const float*)d_in[16];
  const float* fW    = (const float*)d_in[17];
  const float* fb    = (const float*)d_in[18];
  const float* ln_g  = (const float*)d_in[19];
  const float* ln_b  = (const float*)d_in[20];
  const float* nW1   = (const float*)d_in[21];
  const float* nb1   = (const float*)d_in[22];
  const float* nW2   = (const float*)d_in[23];
  const float* nb2   = (const float*)d_in[24];

  float* out  = (float*)d_out;                  // [BN][32] at offset 0
  float* attn = out + (size_t)BN * OO;          // [B,N,N,4] region (268MB)

  float* ws   = (float*)d_ws;
  float* Wh   = ws;                             // [BN][128]
  float* srcv = Wh + (size_t)BN * 128;          // [BN][4]
  float* dstv = srcv + (size_t)BN * 4;          // [BN][4]
  float* gat  = dstv + (size_t)BN * 4;          // [BN][128]

  gru_fused_kernel<<<512, 512, 0, stream>>>(seq, Wih0, Whh0, bih0, bhh0,
                                            Wih1, Whh1, bih1, bhh1,
                                            gatW, a_src, a_dst, Wh, srcv, dstv);
  attn_kernel<<<512, 256, 0, stream>>>(Wh, srcv, dstv, adj, attn, gat);
  mlp_kernel<<<512, 256, 0, stream>>>(gat, rW1, rb1, rW2, rb2, fW, fb,
                                      ln_g, ln_b, nW1, nb1, nW2, nb2, out);
}

// Round 20
// 183.121 us; speedup vs baseline: 1.6585x; 1.0077x over previous
//
#include <hip/hip_runtime.h>

// Problem constants
#define BB 16
#define TT 32
#define NN 1024
#define DD 64
#define HH 64
#define BN 16384          // B*N
#define GH 128
#define RR 128
#define OO 32

#define LOG2E 1.44269504088896f

typedef __attribute__((ext_vector_type(8))) short short8;
typedef __attribute__((ext_vector_type(4))) float f32x4;
typedef __attribute__((ext_vector_type(8))) _Float16 half8;
typedef __attribute__((ext_vector_type(2))) __fp16 fp16x2;

#define MF16(A, B, C) __builtin_amdgcn_mfma_f32_16x16x32_f16((A), (B), (C), 0, 0, 0)

__device__ __forceinline__ float rcp_fast(float x) {
  return __builtin_amdgcn_rcpf(x);
}
__device__ __forceinline__ float exp2_fast(float x) {
  return __builtin_amdgcn_exp2f(x);
}
__device__ __forceinline__ float sigmoid2(float a) {   // a = x*log2e
  return rcp_fast(1.0f + exp2_fast(-a));
}
__device__ __forceinline__ float tanh2(float a) {      // a = x*log2e
  return fmaf(-2.0f, rcp_fast(exp2_fast(2.0f * a) + 1.0f), 1.0f);
}
__device__ __forceinline__ float tanh_e(float x) {
  return tanh2(x * LOG2E);
}
__device__ __forceinline__ float leaky02(float x) {
  return fmaxf(x, 0.2f * x);
}

// ---------------------------------------------------------------------------
// Fused 2-layer GRU + GAT projection, v9 (unchanged from R18).
// ---------------------------------------------------------------------------
__global__ __launch_bounds__(512, 4) void gru_fused_kernel(
    const float* __restrict__ x,
    const float* __restrict__ Wih0, const float* __restrict__ Whh0,
    const float* __restrict__ bih0, const float* __restrict__ bhh0,
    const float* __restrict__ Wih1, const float* __restrict__ Whh1,
    const float* __restrict__ bih1, const float* __restrict__ bhh1,
    const float* __restrict__ gatW, const float* __restrict__ a_src,
    const float* __restrict__ a_dst,
    float* __restrict__ Wh, float* __restrict__ srcv, float* __restrict__ dstv)
{
  __shared__ _Float16 sX[2][2048];     // [buf][seq*64 + swz(k)] : 8 KB
  __shared__ _Float16 sH0[2][2048];    // 8 KB
  __shared__ _Float16 sH1[2][2048];    // 8 KB

  const int tid = threadIdx.x;
  const int gbase = blockIdx.x * 32;

  const int w = tid >> 6, l = tid & 63;
  const int layer = w >> 2;            // 0 or 1
  const int jt = w & 3;                // 16-col j-group
  const int c = l & 15;                // D col (j) / A row within M-tile
  const int rq = l >> 4;               // A k-chunk / D row-group

  const float* Wih = layer ? Wih1 : Wih0;
  const float* Whh = layer ? Whh1 : Whh0;
  const float* bihp = layer ? bih1 : bih0;
  const float* bhhp = layer ? bhh1 : bhh0;

  // ---- weight fragments: global -> reg, fp16 single-plane, x log2e ----
  half8 wf[3][2][2];
#pragma unroll
  for (int g = 0; g < 3; ++g) {
    const int row = g * 64 + jt * 16 + c;
#pragma unroll
    for (int ks = 0; ks < 2; ++ks) {
      const int col = ks * 32 + (rq << 3);
      float4 i0 = *reinterpret_cast<const float4*>(Wih + row * 64 + col);
      float4 i1 = *reinterpret_cast<const float4*>(Wih + row * 64 + col + 4);
      float4 h0 = *reinterpret_cast<const float4*>(Whh + row * 64 + col);
      float4 h1 = *reinterpret_cast<const float4*>(Whh + row * 64 + col + 4);
      float wi[8] = {i0.x, i0.y, i0.z, i0.w, i1.x, i1.y, i1.z, i1.w};
      float wh[8] = {h0.x, h0.y, h0.z, h0.w, h1.x, h1.y, h1.z, h1.w};
      half8 vih, vhh;
#pragma unroll
      for (int e = 0; e < 8; ++e) {
        vih[e] = (_Float16)(wi[e] * LOG2E);
        vhh[e] = (_Float16)(wh[e] * LOG2E);
      }
      wf[g][0][ks] = vih;
      wf[g][1][ks] = vhh;
    }
  }

  // ---- X staging role ----
  const int sseq = tid >> 4;
  const int kq = (tid & 15) << 2;
  const float* xrow = x + (size_t)(gbase + sseq) * (TT * 64) + kq;
  const int sxoff = sseq * 64 + (kq ^ ((sseq & 7) << 3));

  for (int i = tid; i < 2048; i += 512) {
    sH0[0][i] = (_Float16)0.0f;
    sH1[0][i] = (_Float16)0.0f;
  }

  float4 p = *reinterpret_cast<const float4*>(xrow);
  *reinterpret_cast<fp16x2*>(&sX[0][sxoff])     = __builtin_amdgcn_cvt_pkrtz(p.x, p.y);
  *reinterpret_cast<fp16x2*>(&sX[0][sxoff + 2]) = __builtin_amdgcn_cvt_pkrtz(p.z, p.w);
  p = *reinterpret_cast<const float4*>(xrow + 64);

  const int jj = jt * 16 + c;
  const float br  = (bihp[jj]       + bhhp[jj])      * LOG2E;
  const float bz  = (bihp[64 + jj]  + bhhp[64 + jj]) * LOG2E;
  const float bni = bihp[128 + jj] * LOG2E;
  const float bnh = bhhp[128 + jj] * LOG2E;

  int ao[2][2];
#pragma unroll
  for (int mi = 0; mi < 2; ++mi)
#pragma unroll
    for (int ks = 0; ks < 2; ++ks)
      ao[mi][ks] = (mi * 16 + c) * 64 + (((ks << 5) + (rq << 3)) ^ ((c & 7) << 3));
  int hoff[2][4];
#pragma unroll
  for (int mi = 0; mi < 2; ++mi)
#pragma unroll
    for (int q = 0; q < 4; ++q) {
      const int seq = mi * 16 + (rq << 2) + q;
      hoff[mi][q] = seq * 64 + (jj ^ ((seq & 7) << 3));
    }

  float h[2][4];
#pragma unroll
  for (int mi = 0; mi < 2; ++mi)
#pragma unroll
    for (int q = 0; q < 4; ++q) h[mi][q] = 0.0f;

  for (int t = 0; t <= TT; ++t) {
    __syncthreads();
    const int cb = t & 1, nb = cb ^ 1;
    if (t + 1 < TT) {
      *reinterpret_cast<fp16x2*>(&sX[nb][sxoff])     = __builtin_amdgcn_cvt_pkrtz(p.x, p.y);
      *reinterpret_cast<fp16x2*>(&sX[nb][sxoff + 2]) = __builtin_amdgcn_cvt_pkrtz(p.z, p.w);
    }
    if (t + 2 < TT)
      p = *reinterpret_cast<const float4*>(xrow + (t + 2) * 64);

    const bool active = layer ? (t >= 1) : (t < TT);
    if (active) {
      const _Float16* xsrc = layer ? &sH0[cb][0] : &sX[cb][0];
      const _Float16* hsrc = layer ? &sH1[nb][0] : &sH0[cb][0];
      _Float16* hdst       = layer ? &sH1[cb][0] : &sH0[nb][0];

      f32x4 accr[2], accz[2], accni[2], accnh[2];
#pragma unroll
      for (int mi = 0; mi < 2; ++mi) {
        accr[mi]  = (f32x4){br, br, br, br};
        accz[mi]  = (f32x4){bz, bz, bz, bz};
        accni[mi] = (f32x4){bni, bni, bni, bni};
        accnh[mi] = (f32x4){bnh, bnh, bnh, bnh};
      }

#pragma unroll
      for (int ks = 0; ks < 2; ++ks) {
#pragma unroll
        for (int mi = 0; mi < 2; ++mi) {
          const half8 xa = *reinterpret_cast<const half8*>(xsrc + ao[mi][ks]);
          const half8 ha = *reinterpret_cast<const half8*>(hsrc + ao[mi][ks]);
          accr[mi]  = MF16(xa, wf[0][0][ks], accr[mi]);
          accr[mi]  = MF16(ha, wf[0][1][ks], accr[mi]);
          accz[mi]  = MF16(xa, wf[1][0][ks], accz[mi]);
          accz[mi]  = MF16(ha, wf[1][1][ks], accz[mi]);
          accni[mi] = MF16(xa, wf[2][0][ks], accni[mi]);
          accnh[mi] = MF16(ha, wf[2][1][ks], accnh[mi]);
        }
      }

#pragma unroll
      for (int mi = 0; mi < 2; ++mi)
#pragma unroll
        for (int q = 0; q < 4; ++q) {
          float rg = sigmoid2(accr[mi][q]);
          float zg = sigmoid2(accz[mi][q]);
          float ng = tanh2(fmaf(rg, accnh[mi][q], accni[mi][q]));
          float hv = fmaf(zg, h[mi][q] - ng, ng);   // n + z*(h-n)
          h[mi][q] = hv;
          hdst[hoff[mi][q]] = (_Float16)hv;
        }
    }
  }

  // ---- fused GAT projection epilogue: Wh = h1 @ gatW (+ src/dst) ----
  __syncthreads();
  float* sRed = reinterpret_cast<float*>(&sX[0][0]);
  {
    const int col = (w << 4) + c;
    half8 gb[2];
#pragma unroll
    for (int ks = 0; ks < 2; ++ks)
#pragma unroll
      for (int e = 0; e < 8; ++e) {
        const int k = ks * 32 + (rq << 3) + e;
        gb[ks][e] = (_Float16)gatW[k * 128 + col];
      }
    const float as = a_src[col], ad = a_dst[col];
    f32x4 accw[2];
#pragma unroll
    for (int mi = 0; mi < 2; ++mi) {
      accw[mi] = (f32x4){0.f, 0.f, 0.f, 0.f};
#pragma unroll
      for (int ks = 0; ks < 2; ++ks) {
        const half8 fa = *reinterpret_cast<const half8*>(&sH1[0][0] + ao[mi][ks]);
        accw[mi] = MF16(fa, gb[ks], accw[mi]);
      }
    }
#pragma unroll
    for (int mi = 0; mi < 2; ++mi)
#pragma unroll
      for (int q = 0; q < 4; ++q) {
        const int seq = mi * 16 + (rq << 2) + q;
        Wh[(size_t)(gbase + seq) * 128 + col] = accw[mi][q];
        float s = accw[mi][q] * as, d = accw[mi][q] * ad;
#pragma unroll
        for (int mm = 1; mm < 16; mm <<= 1) {
          s += __shfl_xor(s, mm, 64);
          d += __shfl_xor(d, mm, 64);
        }
        if (c == 0) {
          sRed[w * 32 + seq]       = s;
          sRed[256 + w * 32 + seq] = d;
        }
      }
  }
  __syncthreads();
  if (tid < 256) {
    const int hh = tid >> 6;
    const int rem = tid & 63;
    const int sd = rem >> 5;
    const int ii = rem & 31;
    const float v = sRed[sd * 256 + (hh * 2) * 32 + ii] +
                    sRed[sd * 256 + (hh * 2 + 1) * 32 + ii];
    float* outp = sd ? dstv : srcv;
    outp[(size_t)(gbase + ii) * 4 + hh] = v;
  }
}

// ---------------------------------------------------------------------------
// Attention + gat aggregation + FUSED MLP, v6. The attn block (b, 32-row
// i-tile) holds the full post-elu gat[32x128] tile in registers (accg over
// its 4 waves) -- exactly the mlp v2 block shape. Epilogue: gat -> LDS
// (fp32 sR + fp16 swizzled zA), then the validated mlp v2 phases run
// in-place, writing `out` directly. Deletes the mlp launch and the 16.8 MB
// gat global round-trip. LDS overlaid via 64 KB arena -> 2 blocks/CU.
// ---------------------------------------------------------------------------
__global__ __launch_bounds__(256) void attn_kernel(
    const float* __restrict__ Wh, const float* __restrict__ srcp,
    const float* __restrict__ dstp, const int* __restrict__ adj,
    float* __restrict__ attn_out,
    const float* __restrict__ rW1, const float* __restrict__ rb1,
    const float* __restrict__ rW2, const float* __restrict__ rb2,
    const float* __restrict__ fW,  const float* __restrict__ fb,
    const float* __restrict__ ln_g, const float* __restrict__ ln_b,
    const float* __restrict__ nW1, const float* __restrict__ nb1,
    const float* __restrict__ nW2, const float* __restrict__ nb2,
    float* __restrict__ out)
{
  // 64 KB arena; layout A (attn loop) and layout B (mlp epilogue) overlap.
  __shared__ __align__(16) char sArena[65536];
  // Layout A:
  float* sDst = reinterpret_cast<float*>(sArena);                   // 16384 B
  float* sSrc = reinterpret_cast<float*>(sArena + 16384);           // 512 B
  float* sIS  = reinterpret_cast<float*>(sArena + 16896);           // 512 B
  unsigned int* sAdjW = reinterpret_cast<unsigned int*>(sArena + 17408); // 4096 B
  _Float16* sP = reinterpret_cast<_Float16*>(sArena + 21504);       // 20480 B
  _Float16* sBq = reinterpret_cast<_Float16*>(sArena + 41984);      // 20480 B
#define SP(cur, h, i, j) sP[(((cur) * 4 + (h)) * 32 + (i)) * 40 + (j)]
#define SB(cur, h, f, j) sBq[(((cur) * 4 + (h)) * 32 + (f)) * 40 + (j)]
  // Layout B (epilogue):
  _Float16* zA = reinterpret_cast<_Float16*>(sArena);               // 8192 B
  _Float16* tA = reinterpret_cast<_Float16*>(sArena + 8192);        // 8192 B
  float*    sR = reinterpret_cast<float*>(sArena + 16384);          // 16384 B
  _Float16* wB = reinterpret_cast<_Float16*>(sArena + 32768);       // 32768 B

  const int tid = threadIdx.x;
  const int bid = blockIdx.x;
  const int swzb = ((bid & 7) << 6) | (bid >> 3);     // XCD-cluster swizzle
  const int b = swzb >> 5;
  const int itile = (swzb & 31) << 5;
  const int growbase = b * 1024 + itile;

  for (int idx = tid; idx < 4096; idx += 256)
    sDst[idx] = dstp[(size_t)b * 4096 + idx] * LOG2E;
  if (tid < 128)
    sSrc[tid] = srcp[((size_t)growbase) * 4 + tid] * LOG2E;

  {
    const int row = tid >> 3;
    const int w0 = (tid & 7) << 2;
    const int* arow_g = adj + (size_t)(itile + row) * 1024 + (w0 << 5);
#pragma unroll
    for (int wq = 0; wq < 4; ++wq) {
      unsigned int word = 0;
#pragma unroll
      for (int c4 = 0; c4 < 8; ++c4) {
        int4 v = *reinterpret_cast<const int4*>(arow_g + (wq << 5) + (c4 << 2));
        word |= (unsigned)((v.x != 0) ? 1 : 0) << (c4 * 4 + 0);
        word |= (unsigned)((v.y != 0) ? 1 : 0) << (c4 * 4 + 1);
        word |= (unsigned)((v.z != 0) ? 1 : 0) << (c4 * 4 + 2);
        word |= (unsigned)((v.w != 0) ? 1 : 0) << (c4 * 4 + 3);
      }
      sAdjW[row * 32 + w0 + wq] = word;
    }
  }
  __syncthreads();

  // ---- pass 1: row sums ----
  {
    const int i = tid >> 3;
    const int par = tid & 7;
    const float4 sv = *reinterpret_cast<const float4*>(&sSrc[i * 4]);
    f32x4 acc = (f32x4){0.f, 0.f, 0.f, 0.f};
    const unsigned int bit0 = 1u << par;
    for (int kw = 0; kw < 32; ++kw) {
      const unsigned int word = sAdjW[i * 32 + kw];
#pragma unroll
      for (int e = 0; e < 4; ++e) {
        const int gj = (kw << 5) + (e << 3) + par;
        const float4 dv = *reinterpret_cast<const float4*>(&sDst[gj * 4]);
        const float mf = (word & (bit0 << (e << 3))) ? 1.0f : 0.0f;
        acc[0] = fmaf(mf, exp2_fast(leaky02(sv.x + dv.x)), acc[0]);
        acc[1] = fmaf(mf, exp2_fast(leaky02(sv.y + dv.y)), acc[1]);
        acc[2] = fmaf(mf, exp2_fast(leaky02(sv.z + dv.z)), acc[2]);
        acc[3] = fmaf(mf, exp2_fast(leaky02(sv.w + dv.w)), acc[3]);
      }
    }
#pragma unroll
    for (int m = 1; m < 8; m <<= 1) {
#pragma unroll
      for (int q = 0; q < 4; ++q) acc[q] += __shfl_xor(acc[q], m, 64);
    }
    if (par == 0) {
      float4 isv;
      isv.x = acc[0] > 0.f ? rcp_fast(acc[0]) : -1.0f;
      isv.y = acc[1] > 0.f ? rcp_fast(acc[1]) : -1.0f;
      isv.z = acc[2] > 0.f ? rcp_fast(acc[2]) : -1.0f;
      isv.w = acc[3] > 0.f ? rcp_fast(acc[3]) : -1.0f;
      *reinterpret_cast<float4*>(&sIS[i * 4]) = isv;
    }
  }
  __syncthreads();

  // ---- pass 2: 32 j-tiles, dbuf P/B, single barrier per tile ----
  const int il = tid >> 3;
  const int jsub = tid & 7;
  const int wv = tid >> 6;
  const int l = tid & 63;
  const int jjB = tid & 31;
  const int fcB = tid >> 5;

  const float4 sv4 = *reinterpret_cast<const float4*>(&sSrc[il * 4]);
  const float4 is4 = *reinterpret_cast<const float4*>(&sIS[il * 4]);
  f32x4* arow_out = reinterpret_cast<f32x4*>(
      attn_out + ((size_t)(growbase + il)) * 4096);

  f32x4 accg[2][2];
#pragma unroll
  for (int m = 0; m < 2; ++m)
#pragma unroll
    for (int n = 0; n < 2; ++n) accg[m][n] = (f32x4){0.f, 0.f, 0.f, 0.f};

  const int frow = l & 15, fchunk = l >> 4;

  for (int jt = 0; jt < 32; ++jt) {
    const int j0 = jt << 5;
    const int cur = jt & 1;
    {
      const unsigned int word = sAdjW[il * 32 + jt];
#pragma unroll
      for (int q = 0; q < 4; ++q) {
        const int j = jsub + (q << 3);
        const int gj = j0 + j;
        const float4 dv = *reinterpret_cast<const float4*>(&sDst[gj * 4]);
        const float mf = (word & (1u << j)) ? 1.0f : 0.0f;
        f32x4 a4;
        float ex;
        ex = mf * exp2_fast(leaky02(sv4.x + dv.x)); a4[0] = ex * is4.x; if (is4.x < 0.f) a4[0] = 9.765625e-4f;
        ex = mf * exp2_fast(leaky02(sv4.y + dv.y)); a4[1] = ex * is4.y; if (is4.y < 0.f) a4[1] = 9.765625e-4f;
        ex = mf * exp2_fast(leaky02(sv4.z + dv.z)); a4[2] = ex * is4.z; if (is4.z < 0.f) a4[2] = 9.765625e-4f;
        ex = mf * exp2_fast(leaky02(sv4.w + dv.w)); a4[3] = ex * is4.w; if (is4.w < 0.f) a4[3] = 9.765625e-4f;
        __builtin_nontemporal_store(a4, &arow_out[gj]);
        SP(cur, 0, il, j) = (_Float16)a4[0];
        SP(cur, 1, il, j) = (_Float16)a4[1];
        SP(cur, 2, il, j) = (_Float16)a4[2];
        SP(cur, 3, il, j) = (_Float16)a4[3];
      }
      const float* wrow = Wh + ((size_t)(b * 1024 + j0 + jjB)) * 128 + (fcB << 4);
#pragma unroll
      for (int c4 = 0; c4 < 4; ++c4) {
        float4 v = *reinterpret_cast<const float4*>(wrow + (c4 << 2));
        float vv[4] = {v.x, v.y, v.z, v.w};
#pragma unroll
        for (int e = 0; e < 4; ++e) {
          const int hf = (fcB << 4) + (c4 << 2) + e;
          SB(cur, hf >> 5, hf & 31, jjB) = (_Float16)vv[e];
        }
      }
    }
    __syncthreads();
    {
      half8 pa[2], wb2[2];
#pragma unroll
      for (int m = 0; m < 2; ++m)
        pa[m] = *reinterpret_cast<const half8*>(&SP(cur, wv, m * 16 + frow, fchunk << 3));
#pragma unroll
      for (int n = 0; n < 2; ++n)
        wb2[n] = *reinterpret_cast<const half8*>(&SB(cur, wv, n * 16 + frow, fchunk << 3));
#pragma unroll
      for (int m = 0; m < 2; ++m)
#pragma unroll
        for (int n = 0; n < 2; ++n)
          accg[m][n] = MF16(pa[m], wb2[n], accg[m][n]);
    }
  }

  // ================= fused MLP epilogue (mlp v2, in-place) =================
  __syncthreads();   // layout A dead; safe to overlay
  // gat tile (post-elu) -> sR fp32 + zA fp16 swizzled
#pragma unroll
  for (int m = 0; m < 2; ++m)
#pragma unroll
    for (int n = 0; n < 2; ++n)
#pragma unroll
      for (int q = 0; q < 4; ++q) {
        const int row = m * 16 + (l >> 4) * 4 + q;
        const int col = wv * 32 + n * 16 + (l & 15);
        float v = accg[m][n][q];
        v = v > 0.0f ? v : (exp2_fast(v * LOG2E) - 1.0f);
        sR[row * 128 + col] = v;
        zA[row * 128 + (col ^ ((row & 7) << 3))] = (_Float16)v;
      }
  // stage rW1^T -> wB fp16 swizzled
  for (int idx = tid; idx < 2048; idx += 256) {
    const int n = idx & 127, kc = (idx >> 7) << 3;
    half8 hv;
#pragma unroll
    for (int e = 0; e < 8; ++e) hv[e] = (_Float16)rW1[(kc + e) * 128 + n];
    *reinterpret_cast<half8*>(&wB[n * 128 + (kc ^ ((n & 7) << 3))]) = hv;
  }
  __syncthreads();

  const int c = l & 15, rq = l >> 4;
  const int n0 = wv << 5;

  int aoz[2][4], bo[2][4];
#pragma unroll
  for (int mi = 0; mi < 2; ++mi)
#pragma unroll
    for (int ks = 0; ks < 4; ++ks)
      aoz[mi][ks] = (mi * 16 + c) * 128 + (((ks << 5) + (rq << 3)) ^ ((c & 7) << 3));
#pragma unroll
  for (int ni = 0; ni < 2; ++ni)
#pragma unroll
    for (int ks = 0; ks < 4; ++ks)
      bo[ni][ks] = (n0 + ni * 16 + c) * 128 + (((ks << 5) + (rq << 3)) ^ ((c & 7) << 3));

  // ---- phase 1: t1 = relu(z @ rW1 + rb1) -> tA fp16 ----
  {
    f32x4 acc[2][2];
#pragma unroll
    for (int ni = 0; ni < 2; ++ni) {
      const float bb = rb1[n0 + ni * 16 + c];
#pragma unroll
      for (int mi = 0; mi < 2; ++mi) acc[mi][ni] = (f32x4){bb, bb, bb, bb};
    }
#pragma unroll
    for (int ks = 0; ks < 4; ++ks) {
      half8 av[2], bv[2];
#pragma unroll
      for (int mi = 0; mi < 2; ++mi) av[mi] = *reinterpret_cast<const half8*>(&zA[aoz[mi][ks]]);
#pragma unroll
      for (int ni = 0; ni < 2; ++ni) bv[ni] = *reinterpret_cast<const half8*>(&wB[bo[ni][ks]]);
#pragma unroll
      for (int mi = 0; mi < 2; ++mi)
#pragma unroll
        for (int ni = 0; ni < 2; ++ni)
          acc[mi][ni] = MF16(av[mi], bv[ni], acc[mi][ni]);
    }
#pragma unroll
    for (int mi = 0; mi < 2; ++mi)
#pragma unroll
      for (int ni = 0; ni < 2; ++ni)
#pragma unroll
        for (int q = 0; q < 4; ++q) {
          const int row = mi * 16 + (rq << 2) + q;
          const int col = n0 + ni * 16 + c;
          tA[row * 128 + (col ^ ((row & 7) << 3))] = (_Float16)fmaxf(acc[mi][ni][q], 0.0f);
        }
  }
  __syncthreads();
  // ---- stage rW2^T ----
  for (int idx = tid; idx < 2048; idx += 256) {
    const int n = idx & 127, kc = (idx >> 7) << 3;
    half8 hv;
#pragma unroll
    for (int e = 0; e < 8; ++e) hv[e] = (_Float16)rW2[(kc + e) * 128 + n];
    *reinterpret_cast<half8*>(&wB[n * 128 + (kc ^ ((n & 7) << 3))]) = hv;
  }
  __syncthreads();
  // ---- phase 2: res = relu(z + t1 @ rW2 + rb2) -> sR fp32 ----
  {
    f32x4 acc[2][2];
#pragma unroll
    for (int ni = 0; ni < 2; ++ni) {
      const float bb = rb2[n0 + ni * 16 + c];
#pragma unroll
      for (int mi = 0; mi < 2; ++mi) acc[mi][ni] = (f32x4){bb, bb, bb, bb};
    }
#pragma unroll
    for (int ks = 0; ks < 4; ++ks) {
      half8 av[2], bv[2];
#pragma unroll
      for (int mi = 0; mi < 2; ++mi) av[mi] = *reinterpret_cast<const half8*>(&tA[aoz[mi][ks]]);
#pragma unroll
      for (int ni = 0; ni < 2; ++ni) bv[ni] = *reinterpret_cast<const half8*>(&wB[bo[ni][ks]]);
#pragma unroll
      for (int mi = 0; mi < 2; ++mi)
#pragma unroll
        for (int ni = 0; ni < 2; ++ni)
          acc[mi][ni] = MF16(av[mi], bv[ni], acc[mi][ni]);
    }
#pragma unroll
    for (int mi = 0; mi < 2; ++mi)
#pragma unroll
      for (int ni = 0; ni < 2; ++ni)
#pragma unroll
        for (int q = 0; q < 4; ++q) {
          const int row = mi * 16 + (rq << 2) + q;
          const int col = n0 + ni * 16 + c;
          const float zz = sR[row * 128 + col];
          sR[row * 128 + col] = fmaxf(acc[mi][ni][q] + zz, 0.0f);
        }
  }
  __syncthreads();
  // ---- stage phase 3-5 weights (fp32) into wB region ----
  float* sWf = reinterpret_cast<float*>(wB);
  for (int idx = tid; idx < 4096; idx += 256) sWf[idx] = fW[idx];
  for (int idx = tid; idx < 1024; idx += 256) {
    sWf[4096 + idx] = nW1[idx];
    sWf[5120 + idx] = nW2[idx];
  }
  if (tid < 32) {
    sWf[6144 + tid] = fb[tid];
    sWf[6176 + tid] = ln_g[tid];
    sWf[6208 + tid] = ln_b[tid];
    sWf[6240 + tid] = nb1[tid];
    sWf[6272 + tid] = nb2[tid];
  }
  __syncthreads();

  float* sY  = reinterpret_cast<float*>(zA);
  float* sT2 = reinterpret_cast<float*>(tA);
  const int o = tid & 31, rr2 = tid >> 5;
  // ---- phase 3: y = res @ fW + fb -> LN -> tanh ----
  for (int g = 0; g < 4; ++g) {
    const int r = rr2 + (g << 3);
    float y = sWf[6144 + o];
#pragma unroll 8
    for (int k = 0; k < 128; ++k) y = fmaf(sR[r * 128 + k], sWf[k * 32 + o], y);
    float mu = y;
#pragma unroll
    for (int m = 16; m >= 1; m >>= 1) mu += __shfl_xor(mu, m, 32);
    mu *= (1.0f / 32.0f);
    const float d = y - mu;
    float var = d * d;
#pragma unroll
    for (int m = 16; m >= 1; m >>= 1) var += __shfl_xor(var, m, 32);
    var *= (1.0f / 32.0f);
    const float yn = d * rsqrtf(var + 1e-5f) * sWf[6176 + o] + sWf[6208 + o];
    sY[r * 32 + o] = tanh_e(yn);
  }
  __syncthreads();
  // ---- phase 4: t2 = relu(y @ nW1 + nb1) ----
  for (int g = 0; g < 4; ++g) {
    const int r = rr2 + (g << 3);
    float a = sWf[6240 + o];
#pragma unroll
    for (int k = 0; k < 32; ++k) a = fmaf(sY[r * 32 + k], sWf[4096 + k * 32 + o], a);
    sT2[r * 32 + o] = a > 0.0f ? a : 0.0f;
  }
  __syncthreads();
  // ---- phase 5: out = t2 @ nW2 + nb2 ----
  for (int g = 0; g < 4; ++g) {
    const int r = rr2 + (g << 3);
    float a = sWf[6272 + o];
#pragma unroll
    for (int k = 0; k < 32; ++k) a = fmaf(sT2[r * 32 + k], sWf[5120 + k * 32 + o], a);
    out[(size_t)(growbase + r) * 32 + o] = a;
  }
#undef SP
#undef SB
}

// ---------------------------------------------------------------------------
extern "C" void kernel_launch(void* const* d_in, const int* in_sizes, int n_in,
                              void* d_out, int out_size, void* d_ws, size_t ws_size,
                              hipStream_t stream) {
  const float* seq   = (const float*)d_in[0];
  const int*   adj   = (const int*)d_in[1];
  const float* Wih0  = (const float*)d_in[2];
  const float* Whh0  = (const float*)d_in[3];
  const float* bih0  = (const float*)d_in[4];
  const float* bhh0  = (const float*)d_in[5];
  const float* Wih1  = (const float*)d_in[6];
  const float* Whh1  = (const float*)d_in[7];
  const float* bih1  = (const float*)d_in[8];
  const float* bhh1  = (const float*)d_in[9];
  const float* gatW  = (const float*)d_in[10];
  const float* a_src = (const float*)d_in[11];
  const float* a_dst = (const float*)d_in[12];
  const float* rW1   = (const float*)d_in[13];
  const float* rb1   = (const float*)d_in[14];
  const float* rW2   = (const float*)d_in[15];
  const float* rb2   = (const float*)d_in[16];
  const float* fW    = (const float*)d_in[17];
  const float* fb    = (const float*)d_in[18];
  const float* ln_g  = (const float*)d_in[19];
  const float* ln_b  = (const float*)d_in[20];
  const float* nW1   = (const float*)d_in[21];
  const float* nb1   = (const float*)d_in[22];
  const float* nW2   = (const float*)d_in[23];
  const float* nb2   = (const float*)d_in[24];

  float* out  = (float*)d_out;                  // [BN][32] at offset 0
  float* attn = out + (size_t)BN * OO;          // [B,N,N,4] region (268MB)

  float* ws   = (float*)d_ws;
  float* Wh   = ws;                             // [BN][128]
  float* srcv = Wh + (size_t)BN * 128;          // [BN][4]
  float* dstv = srcv + (size_t)BN * 4;          // [BN][4]

  gru_fused_kernel<<<512, 512, 0, stream>>>(seq, Wih0, Whh0, bih0, bhh0,
                                            Wih1, Whh1, bih1, bhh1,
                                            gatW, a_src, a_dst, Wh, srcv, dstv);
  attn_kernel<<<512, 256, 0, stream>>>(Wh, srcv, dstv, adj, attn,
                                       rW1, rb1, rW2, rb2, fW, fb,
                                       ln_g, ln_b, nW1, nb1, nW2, nb2, out);
}